// Round 2
// baseline (797.249 us; speedup 1.0000x reference)
//
#include <hip/hip_runtime.h>
#include <hip/hip_bf16.h>

#define B_ 8
#define N_ 512
#define D_ 512
#define H_ 8
#define DH_ 64
#define PC_ 60
#define RR_ 121

typedef __hip_bfloat16 bf16;

__device__ inline float bf2f(unsigned short u) {
    union { unsigned int i; float f; } x; x.i = ((unsigned)u) << 16; return x.f;
}
__device__ inline unsigned short f2bf(float f) {
    union { float f; unsigned int i; } x; x.f = f;
    unsigned int r = x.i + 0x7fff + ((x.i >> 16) & 1);   // RNE
    return (unsigned short)(r >> 16);
}

// ---------------- QKV projection: X(4096x512) @ W(512x512) + b -> (B,H,N,DH)
__global__ __launch_bounds__(256) void k_qkv(
    const float* __restrict__ X,
    const float* __restrict__ Wq, const float* __restrict__ bq,
    const float* __restrict__ Wk, const float* __restrict__ bk,
    const float* __restrict__ Wv, const float* __restrict__ bv,
    float* __restrict__ Qo, float* __restrict__ Ko, float* __restrict__ Vo)
{
    const int z = blockIdx.z;
    const float* W    = (z == 0) ? Wq : (z == 1) ? Wk : Wv;
    const float* bias = (z == 0) ? bq : (z == 1) ? bk : bv;
    float* O          = (z == 0) ? Qo : (z == 1) ? Ko : Vo;
    const int m0 = blockIdx.x * 64;
    const int n0 = blockIdx.y * 64;
    __shared__ float As[16][68];
    __shared__ float Bs[16][68];
    const int t = threadIdx.x;
    const int tx = t & 15, ty = t >> 4;
    const int arow = t >> 2;
    const int akk  = (t & 3) * 4;
    const int bkk  = t >> 4;
    const int bcol = (t & 15) * 4;
    float acc[4][4] = {};
    for (int k0 = 0; k0 < 512; k0 += 16) {
        float4 a = *reinterpret_cast<const float4*>(&X[(size_t)(m0 + arow) * 512 + k0 + akk]);
        As[akk + 0][arow] = a.x; As[akk + 1][arow] = a.y;
        As[akk + 2][arow] = a.z; As[akk + 3][arow] = a.w;
        *reinterpret_cast<float4*>(&Bs[bkk][bcol]) =
            *reinterpret_cast<const float4*>(&W[(size_t)(k0 + bkk) * 512 + n0 + bcol]);
        __syncthreads();
#pragma unroll
        for (int k = 0; k < 16; ++k) {
            float4 av  = *reinterpret_cast<const float4*>(&As[k][ty * 4]);
            float4 bv4 = *reinterpret_cast<const float4*>(&Bs[k][tx * 4]);
            float aa[4] = {av.x, av.y, av.z, av.w};
            float bb[4] = {bv4.x, bv4.y, bv4.z, bv4.w};
#pragma unroll
            for (int i = 0; i < 4; ++i)
#pragma unroll
                for (int j = 0; j < 4; ++j)
                    acc[i][j] = fmaf(aa[i], bb[j], acc[i][j]);
        }
        __syncthreads();
    }
    const int c0 = n0 + tx * 4;      // h = c0>>6 constant within tile, dh0 = tx*4
    const int h = c0 >> 6;
    const int dh0 = c0 & 63;
    const float4 bb4 = *reinterpret_cast<const float4*>(&bias[c0]);
#pragma unroll
    for (int i = 0; i < 4; ++i) {
        const int r = m0 + ty * 4 + i;
        const int b = r >> 9, n = r & 511;
        float4 o = make_float4(acc[i][0] + bb4.x, acc[i][1] + bb4.y,
                               acc[i][2] + bb4.z, acc[i][3] + bb4.w);
        *reinterpret_cast<float4*>(&O[(size_t)(((b * H_ + h) * N_) + n) * DH_ + dh0]) = o;
    }
}

// ---------------- qp[b,h,n,r] = q[b,h,n,:] . pos_k[r,:]
__global__ __launch_bounds__(256) void k_qpos(
    const float* __restrict__ Q, const float* __restrict__ pos_k,
    float* __restrict__ QP)
{
    __shared__ float pk[RR_][68];
    __shared__ float qs[32][68];
    const int t = threadIdx.x;
    const int chunk = blockIdx.x;      // (b*8+h)*16 + nc
    const int bh = chunk >> 4;
    const int nc = chunk & 15;
    const float* qrow = Q + (size_t)(bh * N_ + nc * 32) * DH_;
    for (int idx = t; idx < RR_ * DH_; idx += 256) {
        const int r = idx >> 6, d = idx & 63;
        pk[r][d] = pos_k[idx];
    }
    for (int idx = t; idx < 32 * DH_; idx += 256) {
        const int r = idx >> 6, d = idx & 63;
        qs[r][d] = qrow[idx];
    }
    __syncthreads();
    float* out = QP + (size_t)(bh * N_ + nc * 32) * RR_;
    for (int idx = t; idx < 32 * RR_; idx += 256) {
        const int row = idx / RR_;
        const int r = idx - row * RR_;
        float s = 0.f;
#pragma unroll
        for (int d = 0; d < DH_; d += 4) {
            float4 qv = *reinterpret_cast<const float4*>(&qs[row][d]);
            float4 pv = *reinterpret_cast<const float4*>(&pk[r][d]);
            s = fmaf(qv.x, pv.x, s); s = fmaf(qv.y, pv.y, s);
            s = fmaf(qv.z, pv.z, s); s = fmaf(qv.w, pv.w, s);
        }
        out[idx] = s;
    }
}

// ---------------- scores = (q @ k^T + qp[rel]) / 8  -> S(B,H,N,M)
__global__ __launch_bounds__(256) void k_scores(
    const float* __restrict__ Q, const float* __restrict__ K,
    const float* __restrict__ QP, float* __restrict__ S)
{
    const int bh = blockIdx.z;
    const int m0 = blockIdx.x * 64;
    const int n0 = blockIdx.y * 64;
    __shared__ float qsh[64][68];
    __shared__ float ksh[64][68];
    const int t = threadIdx.x;
    const float* qp = Q + (size_t)(bh * N_ + n0) * DH_;
    const float* kp = K + (size_t)(bh * N_ + m0) * DH_;
    {
        const int row = t >> 2;
        const int d0 = (t & 3) * 16;
#pragma unroll
        for (int u = 0; u < 4; ++u) {
            float4 a = *reinterpret_cast<const float4*>(&qp[(size_t)row * DH_ + d0 + u * 4]);
            qsh[d0 + u * 4 + 0][row] = a.x; qsh[d0 + u * 4 + 1][row] = a.y;
            qsh[d0 + u * 4 + 2][row] = a.z; qsh[d0 + u * 4 + 3][row] = a.w;
            float4 b = *reinterpret_cast<const float4*>(&kp[(size_t)row * DH_ + d0 + u * 4]);
            ksh[d0 + u * 4 + 0][row] = b.x; ksh[d0 + u * 4 + 1][row] = b.y;
            ksh[d0 + u * 4 + 2][row] = b.z; ksh[d0 + u * 4 + 3][row] = b.w;
        }
    }
    __syncthreads();
    const int tx = t & 15, ty = t >> 4;
    float acc[4][4] = {};
#pragma unroll 16
    for (int d = 0; d < 64; ++d) {
        float4 av  = *reinterpret_cast<const float4*>(&qsh[d][ty * 4]);
        float4 bv4 = *reinterpret_cast<const float4*>(&ksh[d][tx * 4]);
        float aa[4] = {av.x, av.y, av.z, av.w};
        float bb[4] = {bv4.x, bv4.y, bv4.z, bv4.w};
#pragma unroll
        for (int i = 0; i < 4; ++i)
#pragma unroll
            for (int j = 0; j < 4; ++j)
                acc[i][j] = fmaf(aa[i], bb[j], acc[i][j]);
    }
    const float* qpb = QP + (size_t)bh * N_ * RR_;
    float* outp = S + (size_t)bh * N_ * N_;
#pragma unroll
    for (int i = 0; i < 4; ++i) {
        const int n = n0 + ty * 4 + i;
        float v[4];
#pragma unroll
        for (int j = 0; j < 4; ++j) {
            const int m = m0 + tx * 4 + j;
            int rel = m - n;
            rel = rel < -PC_ ? -PC_ : (rel > PC_ ? PC_ : rel);
            v[j] = (acc[i][j] + qpb[(size_t)n * RR_ + rel + PC_]) * 0.125f;
        }
        *reinterpret_cast<float4*>(&outp[(size_t)n * N_ + m0 + tx * 4]) =
            make_float4(v[0], v[1], v[2], v[3]);
    }
}

// ---------------- conv1: 5x5, 8->16 ch, input S(B,8,512,512) f32 -> Y(B,16,512,512) bf16
__global__ __launch_bounds__(256) void k_conv1(
    const float* __restrict__ X, const float* __restrict__ W,
    const float* __restrict__ bias, bf16* __restrict__ Y)
{
    __shared__ float xs[8][36][36];
    __shared__ float wsh[3200];
    __shared__ float bsh[16];
    const int t = threadIdx.x;
    const int b = blockIdx.z;
    const int n0 = blockIdx.y * 32;
    const int m0 = blockIdx.x * 32;
    for (int idx = t; idx < 3200; idx += 256) wsh[idx] = W[idx];
    if (t < 16) bsh[t] = bias[t];
    for (int idx = t; idx < 8 * 36 * 36; idx += 256) {
        const int ci = idx / 1296;
        const int rem = idx - ci * 1296;
        const int r = rem / 36;
        const int c = rem - r * 36;
        const int gn = n0 - 2 + r;
        const int gm = m0 - 2 + c;
        float v = 0.f;
        if ((unsigned)gn < 512u && (unsigned)gm < 512u)
            v = X[((size_t)(b * 8 + ci) * 512 + gn) * 512 + gm];
        xs[ci][r][c] = v;
    }
    __syncthreads();
    const int tx = t & 31;       // m within tile
    const int ty = t >> 5;       // n quad
    const int ln = ty * 4;
    float acc[4][16];
#pragma unroll
    for (int i = 0; i < 4; ++i)
#pragma unroll
        for (int co = 0; co < 16; ++co) acc[i][co] = bsh[co];
    for (int ci = 0; ci < 8; ++ci) {
#pragma unroll
        for (int dm = 0; dm < 5; ++dm) {
            float xv[8];
#pragma unroll
            for (int r = 0; r < 8; ++r) xv[r] = xs[ci][ln + r][tx + dm];
#pragma unroll
            for (int dn = 0; dn < 5; ++dn) {
                const float4* wp = reinterpret_cast<const float4*>(&wsh[((dn * 5 + dm) * 8 + ci) * 16]);
#pragma unroll
                for (int u = 0; u < 4; ++u) {
                    const float4 w4 = wp[u];
                    const float wv[4] = {w4.x, w4.y, w4.z, w4.w};
#pragma unroll
                    for (int q = 0; q < 4; ++q)
#pragma unroll
                        for (int i = 0; i < 4; ++i)
                            acc[i][u * 4 + q] = fmaf(xv[dn + i], wv[q], acc[i][u * 4 + q]);
                }
            }
        }
    }
    unsigned short* Yu = reinterpret_cast<unsigned short*>(Y);
#pragma unroll
    for (int co = 0; co < 16; ++co)
#pragma unroll
        for (int i = 0; i < 4; ++i)
            Yu[((size_t)(b * 16 + co) * 512 + n0 + ln + i) * 512 + m0 + tx] = f2bf(acc[i][co]);
}

// ---------------- masked instance-norm stats (rows n < VL[b], all m), bf16 input
__global__ __launch_bounds__(256) void k_stats(
    const bf16* __restrict__ Y, const int* __restrict__ VL,
    float* __restrict__ ST)
{
    const int b = blockIdx.z;
    const int c = blockIdx.y;
    const int chunk = blockIdx.x;
    const int vl = VL[b];
    const unsigned short* plane =
        reinterpret_cast<const unsigned short*>(Y) + (size_t)(b * 16 + c) * 512 * 512;
    const int t = threadIdx.x;
    const int nlo = chunk * 128;
    const int cap = nlo + 128;
    const int nhi = cap < vl ? cap : vl;
    float s = 0.f, s2 = 0.f;
    const int col = (t & 63) * 8;
    for (int n = nlo + (t >> 6); n < nhi; n += 4) {
        uint4 v = *reinterpret_cast<const uint4*>(&plane[(size_t)n * 512 + col]);
        const unsigned int w[4] = {v.x, v.y, v.z, v.w};
#pragma unroll
        for (int j = 0; j < 4; ++j) {
            float a = bf2f((unsigned short)(w[j] & 0xffff));
            float bq = bf2f((unsigned short)(w[j] >> 16));
            s += a + bq;
            s2 += a * a + bq * bq;
        }
    }
#pragma unroll
    for (int o = 32; o; o >>= 1) {
        s += __shfl_xor(s, o);
        s2 += __shfl_xor(s2, o);
    }
    __shared__ float red[8];
    const int w = t >> 6;
    if ((t & 63) == 0) { red[w * 2] = s; red[w * 2 + 1] = s2; }
    __syncthreads();
    if (t == 0) {
        s = red[0] + red[2] + red[4] + red[6];
        s2 = red[1] + red[3] + red[5] + red[7];
        atomicAdd(&ST[(b * 16 + c) * 2 + 0], s);
        atomicAdd(&ST[(b * 16 + c) * 2 + 1], s2);
    }
}

__global__ void k_statfin(const float* __restrict__ ST, const int* __restrict__ VL,
                          const float* __restrict__ g, const float* __restrict__ be,
                          float* __restrict__ ST2)
{
    const int i = threadIdx.x;
    if (i < 128) {
        const int b = i >> 4, c = i & 15;
        const float sw = (float)VL[b] * 512.f;
        const float mean = ST[i * 2] / sw;
        const float var = ST[i * 2 + 1] / sw - mean * mean;
        const float scale = g[c] * rsqrtf(var + 1e-7f);
        ST2[i * 2] = scale;
        ST2[i * 2 + 1] = be[c] - mean * scale;
    }
}

// ---------------- conv2: norm+relu fused into staging; 16->8 ch; bf16 in -> S(B,8,512,512) f32
__global__ __launch_bounds__(256) void k_conv2(
    const bf16* __restrict__ Y, const float* __restrict__ ST2,
    const float* __restrict__ W, const float* __restrict__ bias,
    float* __restrict__ S)
{
    __shared__ float xs[8][36][36];
    __shared__ float wsh[3200];
    __shared__ float ssh[16][2];
    __shared__ float bsh[8];
    const int t = threadIdx.x;
    const int b = blockIdx.z;
    const int n0 = blockIdx.y * 32;
    const int m0 = blockIdx.x * 32;
    const unsigned short* Yu = reinterpret_cast<const unsigned short*>(Y);
    for (int idx = t; idx < 3200; idx += 256) wsh[idx] = W[idx];
    if (t < 32) ssh[t >> 1][t & 1] = ST2[(b * 16 + (t >> 1)) * 2 + (t & 1)];
    if (t < 8) bsh[t] = bias[t];
    const int tx = t & 31;
    const int ty = t >> 5;
    const int ln = ty * 4;
    float acc[4][8] = {};
    for (int cp = 0; cp < 2; ++cp) {
        __syncthreads();   // xs reuse + wsh/ssh visibility
        for (int idx = t; idx < 8 * 36 * 36; idx += 256) {
            const int ci = idx / 1296;
            const int rem = idx - ci * 1296;
            const int r = rem / 36;
            const int c = rem - r * 36;
            const int gn = n0 - 2 + r;
            const int gm = m0 - 2 + c;
            const int gci = cp * 8 + ci;
            float v = 0.f;
            if ((unsigned)gn < 512u && (unsigned)gm < 512u) {
                v = bf2f(Yu[((size_t)(b * 16 + gci) * 512 + gn) * 512 + gm]);
                v = fmaf(v, ssh[gci][0], ssh[gci][1]);
                v = v > 0.f ? v : 0.f;
            }
            xs[ci][r][c] = v;
        }
        __syncthreads();
        for (int ci = 0; ci < 8; ++ci) {
            const int gci = cp * 8 + ci;
#pragma unroll
            for (int dm = 0; dm < 5; ++dm) {
                float xv[8];
#pragma unroll
                for (int r = 0; r < 8; ++r) xv[r] = xs[ci][ln + r][tx + dm];
#pragma unroll
                for (int dn = 0; dn < 5; ++dn) {
                    const float4* wp = reinterpret_cast<const float4*>(&wsh[((dn * 5 + dm) * 16 + gci) * 8]);
                    const float4 w0 = wp[0], w1 = wp[1];
                    const float wv[8] = {w0.x, w0.y, w0.z, w0.w, w1.x, w1.y, w1.z, w1.w};
#pragma unroll
                    for (int q = 0; q < 8; ++q)
#pragma unroll
                        for (int i = 0; i < 4; ++i)
                            acc[i][q] = fmaf(xv[dn + i], wv[q], acc[i][q]);
                }
            }
        }
    }
#pragma unroll
    for (int co = 0; co < 8; ++co)
#pragma unroll
        for (int i = 0; i < 4; ++i)
            S[((size_t)(b * 8 + co) * 512 + n0 + ln + i) * 512 + m0 + tx] = acc[i][co] + bsh[co];
}

// ---------------- masked softmax over m, in place
__global__ __launch_bounds__(256) void k_softmax(float* __restrict__ S,
                                                 const int* __restrict__ VL)
{
    const int row = blockIdx.x * 4 + (threadIdx.x >> 6);   // (b*8+h)*512 + n
    const int lane = threadIdx.x & 63;
    const int b = row >> 12;
    const int vl = VL[b];
    float* p = S + (size_t)row * 512;
    float4 v0 = reinterpret_cast<float4*>(p)[lane];
    float4 v1 = reinterpret_cast<float4*>(p)[64 + lane];
    float vals[8] = {v0.x, v0.y, v0.z, v0.w, v1.x, v1.y, v1.z, v1.w};
    const int base0 = lane * 4, base1 = 256 + lane * 4;
    float mx = -3.0e38f;
#pragma unroll
    for (int j = 0; j < 8; ++j) {
        const int m = (j < 4) ? (base0 + j) : (base1 + j - 4);
        if (m >= vl) vals[j] = -3.0e38f;
        mx = fmaxf(mx, vals[j]);
    }
#pragma unroll
    for (int o = 32; o; o >>= 1) mx = fmaxf(mx, __shfl_xor(mx, o));
    float sum = 0.f;
#pragma unroll
    for (int j = 0; j < 8; ++j) {
        const float e = __expf(vals[j] - mx);
        vals[j] = e;
        sum += e;
    }
#pragma unroll
    for (int o = 32; o; o >>= 1) sum += __shfl_xor(sum, o);
    const float inv = 1.0f / sum;
    reinterpret_cast<float4*>(p)[lane] =
        make_float4(vals[0] * inv, vals[1] * inv, vals[2] * inv, vals[3] * inv);
    reinterpret_cast<float4*>(p)[64 + lane] =
        make_float4(vals[4] * inv, vals[5] * inv, vals[6] * inv, vals[7] * inv);
}

// ---------------- out = attn(512x512) @ V(512x64) per (b,h)
__global__ __launch_bounds__(256) void k_av(
    const float* __restrict__ A, const float* __restrict__ V,
    float* __restrict__ O)
{
    const int bh = blockIdx.y;
    const int n0 = blockIdx.x * 64;
    __shared__ float As[32][68];
    __shared__ float Vs[32][68];
    const float* Ap = A + (size_t)bh * 512 * 512;
    const float* Vp = V + (size_t)bh * 512 * 64;
    const int t = threadIdx.x;
    const int tx = t & 15, ty = t >> 4;
    float acc[4][4] = {};
    for (int k0 = 0; k0 < 512; k0 += 32) {
#pragma unroll
        for (int u = 0; u < 2; ++u) {
            const int f = t + u * 256;
            const int row = f >> 3;
            const int kk = (f & 7) * 4;
            float4 a = *reinterpret_cast<const float4*>(&Ap[(size_t)(n0 + row) * 512 + k0 + kk]);
            As[kk + 0][row] = a.x; As[kk + 1][row] = a.y;
            As[kk + 2][row] = a.z; As[kk + 3][row] = a.w;
            const int vrow = f >> 4;
            const int vcol = (f & 15) * 4;
            *reinterpret_cast<float4*>(&Vs[vrow][vcol]) =
                *reinterpret_cast<const float4*>(&Vp[(size_t)(k0 + vrow) * 64 + vcol]);
        }
        __syncthreads();
#pragma unroll
        for (int k = 0; k < 32; ++k) {
            float4 av  = *reinterpret_cast<const float4*>(&As[k][ty * 4]);
            float4 bv4 = *reinterpret_cast<const float4*>(&Vs[k][tx * 4]);
            float aa[4] = {av.x, av.y, av.z, av.w};
            float bb[4] = {bv4.x, bv4.y, bv4.z, bv4.w};
#pragma unroll
            for (int i = 0; i < 4; ++i)
#pragma unroll
                for (int j = 0; j < 4; ++j)
                    acc[i][j] = fmaf(aa[i], bb[j], acc[i][j]);
        }
        __syncthreads();
    }
#pragma unroll
    for (int i = 0; i < 4; ++i) {
        float4 o = make_float4(acc[i][0], acc[i][1], acc[i][2], acc[i][3]);
        *reinterpret_cast<float4*>(&O[(size_t)bh * 512 * 64 + (size_t)(n0 + ty * 4 + i) * 64 + tx * 4]) = o;
    }
}

// ---------------- out-proj: gather O(B,H,N,DH) rows -> @ Wh + bh + query -> P(B,N,D)
__global__ __launch_bounds__(256) void k_out(
    const float* __restrict__ O, const float* __restrict__ W,
    const float* __restrict__ bias, const float* __restrict__ X,
    float* __restrict__ P)
{
    const int m0 = blockIdx.x * 64;
    const int n0 = blockIdx.y * 64;
    __shared__ float As[16][68];
    __shared__ float Bs[16][68];
    const int t = threadIdx.x;
    const int tx = t & 15, ty = t >> 4;
    const int arow = t >> 2;
    const int akk  = (t & 3) * 4;
    const int bkk  = t >> 4;
    const int bcol = (t & 15) * 4;
    const int r_ = m0 + arow;
    const int bb_ = r_ >> 9;
    const int nn_ = r_ & 511;
    float acc[4][4] = {};
    for (int k0 = 0; k0 < 512; k0 += 16) {
        const int k = k0 + akk;
        const int h = k >> 6;
        const int dh = k & 63;
        float4 a = *reinterpret_cast<const float4*>(&O[(size_t)((bb_ * 8 + h) * 512 + nn_) * 64 + dh]);
        As[akk + 0][arow] = a.x; As[akk + 1][arow] = a.y;
        As[akk + 2][arow] = a.z; As[akk + 3][arow] = a.w;
        *reinterpret_cast<float4*>(&Bs[bkk][bcol]) =
            *reinterpret_cast<const float4*>(&W[(size_t)(k0 + bkk) * 512 + n0 + bcol]);
        __syncthreads();
#pragma unroll
        for (int k2 = 0; k2 < 16; ++k2) {
            float4 av  = *reinterpret_cast<const float4*>(&As[k2][ty * 4]);
            float4 bv4 = *reinterpret_cast<const float4*>(&Bs[k2][tx * 4]);
            float aa[4] = {av.x, av.y, av.z, av.w};
            float bb[4] = {bv4.x, bv4.y, bv4.z, bv4.w};
#pragma unroll
            for (int i = 0; i < 4; ++i)
#pragma unroll
                for (int j = 0; j < 4; ++j)
                    acc[i][j] = fmaf(aa[i], bb[j], acc[i][j]);
        }
        __syncthreads();
    }
    const int c0 = n0 + tx * 4;
    const float4 bb4 = *reinterpret_cast<const float4*>(&bias[c0]);
#pragma unroll
    for (int i = 0; i < 4; ++i) {
        const int r = m0 + ty * 4 + i;
        const float4 q4 = *reinterpret_cast<const float4*>(&X[(size_t)r * 512 + c0]);
        float4 o = make_float4(acc[i][0] + bb4.x + q4.x, acc[i][1] + bb4.y + q4.y,
                               acc[i][2] + bb4.z + q4.z, acc[i][3] + bb4.w + q4.w);
        *reinterpret_cast<float4*>(&P[(size_t)r * 512 + c0]) = o;
    }
}

// ---------------- final LayerNorm over D=512
__global__ __launch_bounds__(256) void k_ln(
    const float* __restrict__ P, const float* __restrict__ g,
    const float* __restrict__ be, float* __restrict__ out)
{
    const int row = blockIdx.x * 4 + (threadIdx.x >> 6);
    const int lane = threadIdx.x & 63;
    const float* p = P + (size_t)row * 512;
    float4 v0 = reinterpret_cast<const float4*>(p)[lane];
    float4 v1 = reinterpret_cast<const float4*>(p)[64 + lane];
    float s = v0.x + v0.y + v0.z + v0.w + v1.x + v1.y + v1.z + v1.w;
#pragma unroll
    for (int o = 32; o; o >>= 1) s += __shfl_xor(s, o);
    const float mean = s * (1.0f / 512.0f);
    float d[8] = {v0.x - mean, v0.y - mean, v0.z - mean, v0.w - mean,
                  v1.x - mean, v1.y - mean, v1.z - mean, v1.w - mean};
    float s2 = 0.f;
#pragma unroll
    for (int j = 0; j < 8; ++j) s2 += d[j] * d[j];
#pragma unroll
    for (int o = 32; o; o >>= 1) s2 += __shfl_xor(s2, o);
    const float rstd = rsqrtf(s2 * (1.0f / 512.0f) + 1e-7f);
    float4 g0 = reinterpret_cast<const float4*>(g)[lane];
    float4 g1 = reinterpret_cast<const float4*>(g)[64 + lane];
    float4 b0 = reinterpret_cast<const float4*>(be)[lane];
    float4 b1 = reinterpret_cast<const float4*>(be)[64 + lane];
    float* op = out + (size_t)row * 512;
    reinterpret_cast<float4*>(op)[lane] =
        make_float4(d[0] * rstd * g0.x + b0.x, d[1] * rstd * g0.y + b0.y,
                    d[2] * rstd * g0.z + b0.z, d[3] * rstd * g0.w + b0.w);
    reinterpret_cast<float4*>(op)[64 + lane] =
        make_float4(d[4] * rstd * g1.x + b1.x, d[5] * rstd * g1.y + b1.y,
                    d[6] * rstd * g1.z + b1.z, d[7] * rstd * g1.w + b1.w);
}

extern "C" void kernel_launch(void* const* d_in, const int* in_sizes, int n_in,
                              void* d_out, int out_size, void* d_ws, size_t ws_size,
                              hipStream_t stream)
{
    const float* query = (const float*)d_in[0];
    const int*   VL    = (const int*)d_in[1];
    const float* Wq = (const float*)d_in[2];  const float* bq = (const float*)d_in[3];
    const float* Wk = (const float*)d_in[4];  const float* bk = (const float*)d_in[5];
    const float* Wv = (const float*)d_in[6];  const float* bv = (const float*)d_in[7];
    const float* Wh = (const float*)d_in[8];  const float* bh = (const float*)d_in[9];
    const float* pos_k = (const float*)d_in[10];
    const float* c1w = (const float*)d_in[11]; const float* c1b = (const float*)d_in[12];
    const float* n1g = (const float*)d_in[13]; const float* n1b = (const float*)d_in[14];
    const float* c2w = (const float*)d_in[15]; const float* c2b = (const float*)d_in[16];
    const float* lng = (const float*)d_in[17]; const float* lnb = (const float*)d_in[18];

    float* ws = (float*)d_ws;
    const size_t M1 = (size_t)1 << 20;   // 1M floats
    // Float-offset layout (peak 34M floats + 512 = ~136 MB):
    //   [0,2M)   Qb        (later reused as O)      } overlapped by Y1h (bf16, 16M
    //   [2M,4M)  Kb        (later reused as P)      }   float-equiv = [0,16M)),
    //   [4M,8M)  QP                                 }   live conv1..conv2 only
    //   [16M,18M) Vb       (live qkv..av)
    //   [18M,34M) S1       scores / attn (16M floats)
    //   [34M,+256) ST, then ST2
    float* Qb = ws;
    float* Kb = ws + 2 * M1;
    float* QP = ws + 4 * M1;
    bf16*  Y1 = (bf16*)ws;                       // 32M bf16 = [0,16M) floats
    float* Vb = ws + 16 * M1;
    float* S1 = ws + 18 * M1;
    float* ST = ws + 34 * M1;
    float* ST2 = ST + 256;
    float* O = Qb;
    float* P = Kb;

    hipMemsetAsync(ST, 0, 256 * sizeof(float), stream);

    k_qkv<<<dim3(64, 8, 3), 256, 0, stream>>>(query, Wq, bq, Wk, bk, Wv, bv, Qb, Kb, Vb);
    k_qpos<<<1024, 256, 0, stream>>>(Qb, pos_k, QP);
    k_scores<<<dim3(8, 8, 64), 256, 0, stream>>>(Qb, Kb, QP, S1);
    k_conv1<<<dim3(16, 16, 8), 256, 0, stream>>>(S1, c1w, c1b, Y1);
    k_stats<<<dim3(4, 16, 8), 256, 0, stream>>>(Y1, VL, ST);
    k_statfin<<<1, 128, 0, stream>>>(ST, VL, n1g, n1b, ST2);
    k_conv2<<<dim3(16, 16, 8), 256, 0, stream>>>(Y1, ST2, c2w, c2b, S1);
    k_softmax<<<8192, 256, 0, stream>>>(S1, VL);
    k_av<<<dim3(8, 64), 256, 0, stream>>>(S1, Vb, O);
    k_out<<<dim3(64, 8), 256, 0, stream>>>(O, Wh, bh, query, P);
    k_ln<<<1024, 256, 0, stream>>>(P, lng, lnb, (float*)d_out);
}

// Round 3
// 452.413 us; speedup vs baseline: 1.7622x; 1.7622x over previous
//
#include <hip/hip_runtime.h>
#include <hip/hip_bf16.h>

#define B_ 8
#define N_ 512
#define D_ 512
#define H_ 8
#define DH_ 64
#define PC_ 60
#define RR_ 121

typedef __hip_bfloat16 bf16;
typedef unsigned short u16;
typedef __attribute__((ext_vector_type(8))) short short8v;   // 8 bf16 (4 VGPR)
typedef __attribute__((ext_vector_type(4))) float f32x4;

__device__ inline float bf2f(u16 u) {
    union { unsigned int i; float f; } x; x.i = ((unsigned)u) << 16; return x.f;
}
__device__ inline u16 f2bf(float f) {
    union { float f; unsigned int i; } x; x.f = f;
    unsigned int r = x.i + 0x7fff + ((x.i >> 16) & 1);   // RNE
    return (u16)(r >> 16);
}

// ---------------- QKV projection: X(4096x512) @ W(512x512) + b -> (B,H,N,DH)
__global__ __launch_bounds__(256) void k_qkv(
    const float* __restrict__ X,
    const float* __restrict__ Wq, const float* __restrict__ bq,
    const float* __restrict__ Wk, const float* __restrict__ bk,
    const float* __restrict__ Wv, const float* __restrict__ bv,
    float* __restrict__ Qo, float* __restrict__ Ko, float* __restrict__ Vo)
{
    const int z = blockIdx.z;
    const float* W    = (z == 0) ? Wq : (z == 1) ? Wk : Wv;
    const float* bias = (z == 0) ? bq : (z == 1) ? bk : bv;
    float* O          = (z == 0) ? Qo : (z == 1) ? Ko : Vo;
    const int m0 = blockIdx.x * 64;
    const int n0 = blockIdx.y * 64;
    __shared__ float As[16][68];
    __shared__ float Bs[16][68];
    const int t = threadIdx.x;
    const int tx = t & 15, ty = t >> 4;
    const int arow = t >> 2;
    const int akk  = (t & 3) * 4;
    const int bkk  = t >> 4;
    const int bcol = (t & 15) * 4;
    float acc[4][4] = {};
    for (int k0 = 0; k0 < 512; k0 += 16) {
        float4 a = *reinterpret_cast<const float4*>(&X[(size_t)(m0 + arow) * 512 + k0 + akk]);
        As[akk + 0][arow] = a.x; As[akk + 1][arow] = a.y;
        As[akk + 2][arow] = a.z; As[akk + 3][arow] = a.w;
        *reinterpret_cast<float4*>(&Bs[bkk][bcol]) =
            *reinterpret_cast<const float4*>(&W[(size_t)(k0 + bkk) * 512 + n0 + bcol]);
        __syncthreads();
#pragma unroll
        for (int k = 0; k < 16; ++k) {
            float4 av  = *reinterpret_cast<const float4*>(&As[k][ty * 4]);
            float4 bv4 = *reinterpret_cast<const float4*>(&Bs[k][tx * 4]);
            float aa[4] = {av.x, av.y, av.z, av.w};
            float bb[4] = {bv4.x, bv4.y, bv4.z, bv4.w};
#pragma unroll
            for (int i = 0; i < 4; ++i)
#pragma unroll
                for (int j = 0; j < 4; ++j)
                    acc[i][j] = fmaf(aa[i], bb[j], acc[i][j]);
        }
        __syncthreads();
    }
    const int c0 = n0 + tx * 4;
    const int h = c0 >> 6;
    const int dh0 = c0 & 63;
    const float4 bb4 = *reinterpret_cast<const float4*>(&bias[c0]);
#pragma unroll
    for (int i = 0; i < 4; ++i) {
        const int r = m0 + ty * 4 + i;
        const int b = r >> 9, n = r & 511;
        float4 o = make_float4(acc[i][0] + bb4.x, acc[i][1] + bb4.y,
                               acc[i][2] + bb4.z, acc[i][3] + bb4.w);
        *reinterpret_cast<float4*>(&O[(size_t)(((b * H_ + h) * N_) + n) * DH_ + dh0]) = o;
    }
}

// ---------------- qp[b,h,n,r] = q[b,h,n,:] . pos_k[r,:]
__global__ __launch_bounds__(256) void k_qpos(
    const float* __restrict__ Q, const float* __restrict__ pos_k,
    float* __restrict__ QP)
{
    __shared__ float pk[RR_][68];
    __shared__ float qs[32][68];
    const int t = threadIdx.x;
    const int chunk = blockIdx.x;      // (b*8+h)*16 + nc
    const int bh = chunk >> 4;
    const int nc = chunk & 15;
    const float* qrow = Q + (size_t)(bh * N_ + nc * 32) * DH_;
    for (int idx = t; idx < RR_ * DH_; idx += 256) {
        const int r = idx >> 6, d = idx & 63;
        pk[r][d] = pos_k[idx];
    }
    for (int idx = t; idx < 32 * DH_; idx += 256) {
        const int r = idx >> 6, d = idx & 63;
        qs[r][d] = qrow[idx];
    }
    __syncthreads();
    float* out = QP + (size_t)(bh * N_ + nc * 32) * RR_;
    for (int idx = t; idx < 32 * RR_; idx += 256) {
        const int row = idx / RR_;
        const int r = idx - row * RR_;
        float s = 0.f;
#pragma unroll
        for (int d = 0; d < DH_; d += 4) {
            float4 qv = *reinterpret_cast<const float4*>(&qs[row][d]);
            float4 pv = *reinterpret_cast<const float4*>(&pk[r][d]);
            s = fmaf(qv.x, pv.x, s); s = fmaf(qv.y, pv.y, s);
            s = fmaf(qv.z, pv.z, s); s = fmaf(qv.w, pv.w, s);
        }
        out[idx] = s;
    }
}

// ---------------- scores = (q @ k^T + qp[rel]) / 8  -> S(B,H,N,M)
__global__ __launch_bounds__(256) void k_scores(
    const float* __restrict__ Q, const float* __restrict__ K,
    const float* __restrict__ QP, float* __restrict__ S)
{
    const int bh = blockIdx.z;
    const int m0 = blockIdx.x * 64;
    const int n0 = blockIdx.y * 64;
    __shared__ float qsh[64][68];
    __shared__ float ksh[64][68];
    const int t = threadIdx.x;
    const float* qp = Q + (size_t)(bh * N_ + n0) * DH_;
    const float* kp = K + (size_t)(bh * N_ + m0) * DH_;
    {
        const int row = t >> 2;
        const int d0 = (t & 3) * 16;
#pragma unroll
        for (int u = 0; u < 4; ++u) {
            float4 a = *reinterpret_cast<const float4*>(&qp[(size_t)row * DH_ + d0 + u * 4]);
            qsh[d0 + u * 4 + 0][row] = a.x; qsh[d0 + u * 4 + 1][row] = a.y;
            qsh[d0 + u * 4 + 2][row] = a.z; qsh[d0 + u * 4 + 3][row] = a.w;
            float4 b = *reinterpret_cast<const float4*>(&kp[(size_t)row * DH_ + d0 + u * 4]);
            ksh[d0 + u * 4 + 0][row] = b.x; ksh[d0 + u * 4 + 1][row] = b.y;
            ksh[d0 + u * 4 + 2][row] = b.z; ksh[d0 + u * 4 + 3][row] = b.w;
        }
    }
    __syncthreads();
    const int tx = t & 15, ty = t >> 4;
    float acc[4][4] = {};
#pragma unroll 16
    for (int d = 0; d < 64; ++d) {
        float4 av  = *reinterpret_cast<const float4*>(&qsh[d][ty * 4]);
        float4 bv4 = *reinterpret_cast<const float4*>(&ksh[d][tx * 4]);
        float aa[4] = {av.x, av.y, av.z, av.w};
        float bb[4] = {bv4.x, bv4.y, bv4.z, bv4.w};
#pragma unroll
        for (int i = 0; i < 4; ++i)
#pragma unroll
            for (int j = 0; j < 4; ++j)
                acc[i][j] = fmaf(aa[i], bb[j], acc[i][j]);
    }
    const float* qpb = QP + (size_t)bh * N_ * RR_;
    float* outp = S + (size_t)bh * N_ * N_;
#pragma unroll
    for (int i = 0; i < 4; ++i) {
        const int n = n0 + ty * 4 + i;
        float v[4];
#pragma unroll
        for (int j = 0; j < 4; ++j) {
            const int m = m0 + tx * 4 + j;
            int rel = m - n;
            rel = rel < -PC_ ? -PC_ : (rel > PC_ ? PC_ : rel);
            v[j] = (acc[i][j] + qpb[(size_t)n * RR_ + rel + PC_]) * 0.125f;
        }
        *reinterpret_cast<float4*>(&outp[(size_t)n * N_ + m0 + tx * 4]) =
            make_float4(v[0], v[1], v[2], v[3]);
    }
}

// ---------------- weight-fragment prep: HWIO f32 -> MFMA lane-layout bf16 frags
// Wf1: 7 chunks (K=224, pad 25->28 taps), N=16.  Wf2: 13 chunks (K=416, 50 groups), N=8 (pad 16).
__global__ void k_wprep(const float* __restrict__ c1w, const float* __restrict__ c2w,
                        u16* __restrict__ Wf1, u16* __restrict__ Wf2)
{
    const int t = threadIdx.x;
    for (int s = t; s < 448; s += 256) {
        const int q = s >> 6, l = s & 63, lg = l >> 4, n = l & 15;
        const int G = q * 4 + lg;
        unsigned o[4];
#pragma unroll
        for (int u2 = 0; u2 < 4; ++u2) {
            float v0 = 0.f, v1 = 0.f;
            if (G < 25) {
                const int dn = G / 5, dm = G - dn * 5;
                v0 = c1w[((dn * 5 + dm) * 8 + u2 * 2 + 0) * 16 + n];
                v1 = c1w[((dn * 5 + dm) * 8 + u2 * 2 + 1) * 16 + n];
            }
            o[u2] = f2bf(v0) | ((unsigned)f2bf(v1) << 16);
        }
        *reinterpret_cast<uint4*>(&Wf1[s * 8]) = make_uint4(o[0], o[1], o[2], o[3]);
    }
    for (int s = t; s < 832; s += 256) {
        const int q = s >> 6, l = s & 63, lg = l >> 4, n = l & 15;
        const int G = q * 4 + lg;
        unsigned o[4];
#pragma unroll
        for (int u2 = 0; u2 < 4; ++u2) {
            float v0 = 0.f, v1 = 0.f;
            if (G < 50 && n < 8) {
                const int pos = G >> 1, h = G & 1;
                const int dn = pos / 5, dm = pos - dn * 5;
                v0 = c2w[((dn * 5 + dm) * 16 + h * 8 + u2 * 2 + 0) * 8 + n];
                v1 = c2w[((dn * 5 + dm) * 16 + h * 8 + u2 * 2 + 1) * 8 + n];
            }
            o[u2] = f2bf(v0) | ((unsigned)f2bf(v1) << 16);
        }
        *reinterpret_cast<uint4*>(&Wf2[s * 8]) = make_uint4(o[0], o[1], o[2], o[3]);
    }
}

// ---------------- conv1 (MFMA): S(B,8,512,512) f32 -> Y(B,512,512,16) bf16 channel-last
// + fused masked-norm statistics (rows n < VL[b]) via atomics into ST.
__global__ __launch_bounds__(256) void k_conv1m(
    const float* __restrict__ S, const u16* __restrict__ Wf,
    const float* __restrict__ bias, u16* __restrict__ Y,
    const int* __restrict__ VL, float* __restrict__ ST)
{
    __shared__ __align__(16) u16 xs[10368];          // 36*36 pixels x 8ch bf16
    __shared__ float wred[4][16][2];
    const int t = threadIdx.x;
    const int b = blockIdx.z;
    const int n0 = blockIdx.y * 32;
    const int m0 = blockIdx.x * 32;
    const float* sp0 = S + (size_t)(b * 8) * 262144;
    for (int idx = t; idx < 1296; idx += 256) {
        const int r = idx / 36; const int c = idx - r * 36;
        const int gn = n0 - 2 + r, gm = m0 - 2 + c;
        uint4 pk = make_uint4(0, 0, 0, 0);
        if ((unsigned)gn < 512u && (unsigned)gm < 512u) {
            const float* p = sp0 + (size_t)gn * 512 + gm;
            float v[8];
#pragma unroll
            for (int e = 0; e < 8; ++e) v[e] = p[(size_t)e * 262144];
            pk.x = f2bf(v[0]) | ((unsigned)f2bf(v[1]) << 16);
            pk.y = f2bf(v[2]) | ((unsigned)f2bf(v[3]) << 16);
            pk.z = f2bf(v[4]) | ((unsigned)f2bf(v[5]) << 16);
            pk.w = f2bf(v[6]) | ((unsigned)f2bf(v[7]) << 16);
        }
        *reinterpret_cast<uint4*>(&xs[idx * 8]) = pk;
    }
    const int lane = t & 63, wave = t >> 6;
    const int lg = lane >> 4, ln16 = lane & 15;
    short8v bq[7];
#pragma unroll
    for (int q = 0; q < 7; ++q)
        bq[q] = *reinterpret_cast<const short8v*>(&Wf[(q * 64 + lane) * 8]);
    int aoff[7];
#pragma unroll
    for (int q = 0; q < 7; ++q) {
        const int G = q * 4 + lg; const int p = (G < 25) ? G : 0;
        const int dn = p / 5, dm = p - dn * 5;
        aoff[q] = (dn * 36 + dm) * 8;
    }
    const float bs = bias[ln16];
    const int vl = VL[b];
    float sst = 0.f, sst2 = 0.f;
    __syncthreads();
    for (int i = 0; i < 16; ++i) {
        const int j = wave * 16 + i;
        const int tr = j >> 1, c0 = (j & 1) << 4;
        const int pb = (tr * 36 + c0 + ln16) * 8;
        f32x4 acc = {bs, bs, bs, bs};
#pragma unroll
        for (int q = 0; q < 7; ++q) {
            short8v a = *reinterpret_cast<const short8v*>(&xs[pb + aoff[q]]);
            acc = __builtin_amdgcn_mfma_f32_16x16x32_bf16(a, bq[q], acc, 0, 0, 0);
        }
        u16* yp = Y + (((size_t)(b * 512 + n0 + tr)) * 512 + (m0 + c0 + lg * 4)) * 16 + ln16;
        yp[0]  = f2bf(acc[0]); yp[16] = f2bf(acc[1]);
        yp[32] = f2bf(acc[2]); yp[48] = f2bf(acc[3]);
        if (n0 + tr < vl) {
            sst  += acc[0] + acc[1] + acc[2] + acc[3];
            sst2 += acc[0]*acc[0] + acc[1]*acc[1] + acc[2]*acc[2] + acc[3]*acc[3];
        }
    }
    sst  += __shfl_xor(sst, 16);  sst  += __shfl_xor(sst, 32);
    sst2 += __shfl_xor(sst2, 16); sst2 += __shfl_xor(sst2, 32);
    if (lane < 16) { wred[wave][lane][0] = sst; wred[wave][lane][1] = sst2; }
    __syncthreads();
    if (t < 16) {
        const float a  = wred[0][t][0] + wred[1][t][0] + wred[2][t][0] + wred[3][t][0];
        const float b2 = wred[0][t][1] + wred[1][t][1] + wred[2][t][1] + wred[3][t][1];
        atomicAdd(&ST[(b * 16 + t) * 2 + 0], a);
        atomicAdd(&ST[(b * 16 + t) * 2 + 1], b2);
    }
}

__global__ void k_statfin(const float* __restrict__ ST, const int* __restrict__ VL,
                          const float* __restrict__ g, const float* __restrict__ be,
                          float* __restrict__ ST2)
{
    const int i = threadIdx.x;
    if (i < 128) {
        const int b = i >> 4, c = i & 15;
        const float sw = (float)VL[b] * 512.f;
        const float mean = ST[i * 2] / sw;
        const float var = ST[i * 2 + 1] / sw - mean * mean;
        const float scale = g[c] * rsqrtf(var + 1e-7f);
        ST2[i * 2] = scale;
        ST2[i * 2 + 1] = be[c] - mean * scale;
    }
}

// ---------------- conv2 (MFMA): Y(B,512,512,16) bf16 channel-last, norm+relu fused in staging
// -> S2(B,8,512,512) f32 planar
__global__ __launch_bounds__(256) void k_conv2m(
    const u16* __restrict__ Y, const float* __restrict__ ST2,
    const u16* __restrict__ Wf, const float* __restrict__ bias,
    float* __restrict__ S2)
{
    __shared__ __align__(16) u16 xs[20736];          // two 8-ch halves: [0,10368) and [10368,20736)
    const int t = threadIdx.x;
    const int b = blockIdx.z;
    const int n0 = blockIdx.y * 32, m0 = blockIdx.x * 32;
    float sc[16], sh[16];
#pragma unroll
    for (int ch = 0; ch < 16; ++ch) {
        sc[ch] = ST2[(b * 16 + ch) * 2 + 0];
        sh[ch] = ST2[(b * 16 + ch) * 2 + 1];
    }
    for (int idx = t; idx < 1296; idx += 256) {
        const int r = idx / 36; const int c = idx - r * 36;
        const int gn = n0 - 2 + r, gm = m0 - 2 + c;
        uint4 p0 = make_uint4(0, 0, 0, 0), p1 = p0;
        if ((unsigned)gn < 512u && (unsigned)gm < 512u) {
            const u16* yp = Y + (((size_t)(b * 512 + gn)) * 512 + gm) * 16;
            const uint4 r0 = *reinterpret_cast<const uint4*>(yp);
            const uint4 r1 = *reinterpret_cast<const uint4*>(yp + 8);
            const unsigned w0[4] = {r0.x, r0.y, r0.z, r0.w};
            const unsigned w1[4] = {r1.x, r1.y, r1.z, r1.w};
            unsigned o0[4], o1[4];
#pragma unroll
            for (int u2 = 0; u2 < 4; ++u2) {
                const int ch = u2 * 2;
                float a0 = bf2f((u16)(w0[u2] & 0xffff));
                float a1 = bf2f((u16)(w0[u2] >> 16));
                a0 = fmaf(a0, sc[ch], sh[ch]);         a0 = a0 > 0.f ? a0 : 0.f;
                a1 = fmaf(a1, sc[ch + 1], sh[ch + 1]); a1 = a1 > 0.f ? a1 : 0.f;
                o0[u2] = f2bf(a0) | ((unsigned)f2bf(a1) << 16);
                const int ch2 = 8 + u2 * 2;
                float b0 = bf2f((u16)(w1[u2] & 0xffff));
                float b1 = bf2f((u16)(w1[u2] >> 16));
                b0 = fmaf(b0, sc[ch2], sh[ch2]);         b0 = b0 > 0.f ? b0 : 0.f;
                b1 = fmaf(b1, sc[ch2 + 1], sh[ch2 + 1]); b1 = b1 > 0.f ? b1 : 0.f;
                o1[u2] = f2bf(b0) | ((unsigned)f2bf(b1) << 16);
            }
            p0 = make_uint4(o0[0], o0[1], o0[2], o0[3]);
            p1 = make_uint4(o1[0], o1[1], o1[2], o1[3]);
        }
        *reinterpret_cast<uint4*>(&xs[idx * 8]) = p0;
        *reinterpret_cast<uint4*>(&xs[10368 + idx * 8]) = p1;
    }
    const int lane = t & 63, wave = t >> 6;
    const int lg = lane >> 4, ln16 = lane & 15;
    short8v bq[13];
#pragma unroll
    for (int q = 0; q < 13; ++q)
        bq[q] = *reinterpret_cast<const short8v*>(&Wf[(q * 64 + lane) * 8]);
    int aoff[13];
#pragma unroll
    for (int q = 0; q < 13; ++q) {
        const int G = q * 4 + lg; const int p = (G < 50) ? G : 0;
        const int pos = p >> 1, h = p & 1;
        const int dn = pos / 5, dm = pos - dn * 5;
        aoff[q] = h * 10368 + (dn * 36 + dm) * 8;
    }
    const float bs = (ln16 < 8) ? bias[ln16] : 0.f;
    __syncthreads();
    for (int i = 0; i < 16; ++i) {
        const int j = wave * 16 + i;
        const int tr = j >> 1, c0 = (j & 1) << 4;
        const int pb = (tr * 36 + c0 + ln16) * 8;
        f32x4 acc = {bs, bs, bs, bs};
#pragma unroll
        for (int q = 0; q < 13; ++q) {
            short8v a = *reinterpret_cast<const short8v*>(&xs[pb + aoff[q]]);
            acc = __builtin_amdgcn_mfma_f32_16x16x32_bf16(a, bq[q], acc, 0, 0, 0);
        }
        if (ln16 < 8) {
            float4 o = make_float4(acc[0], acc[1], acc[2], acc[3]);
            *reinterpret_cast<float4*>(
                &S2[(((size_t)(b * 8 + ln16)) * 512 + n0 + tr) * 512 + m0 + c0 + lg * 4]) = o;
        }
    }
}

// ---------------- masked softmax over m, in place
__global__ __launch_bounds__(256) void k_softmax(float* __restrict__ S,
                                                 const int* __restrict__ VL)
{
    const int row = blockIdx.x * 4 + (threadIdx.x >> 6);   // (b*8+h)*512 + n
    const int lane = threadIdx.x & 63;
    const int b = row >> 12;
    const int vl = VL[b];
    float* p = S + (size_t)row * 512;
    float4 v0 = reinterpret_cast<float4*>(p)[lane];
    float4 v1 = reinterpret_cast<float4*>(p)[64 + lane];
    float vals[8] = {v0.x, v0.y, v0.z, v0.w, v1.x, v1.y, v1.z, v1.w};
    const int base0 = lane * 4, base1 = 256 + lane * 4;
    float mx = -3.0e38f;
#pragma unroll
    for (int j = 0; j < 8; ++j) {
        const int m = (j < 4) ? (base0 + j) : (base1 + j - 4);
        if (m >= vl) vals[j] = -3.0e38f;
        mx = fmaxf(mx, vals[j]);
    }
#pragma unroll
    for (int o = 32; o; o >>= 1) mx = fmaxf(mx, __shfl_xor(mx, o));
    float sum = 0.f;
#pragma unroll
    for (int j = 0; j < 8; ++j) {
        const float e = __expf(vals[j] - mx);
        vals[j] = e;
        sum += e;
    }
#pragma unroll
    for (int o = 32; o; o >>= 1) sum += __shfl_xor(sum, o);
    const float inv = 1.0f / sum;
    reinterpret_cast<float4*>(p)[lane] =
        make_float4(vals[0] * inv, vals[1] * inv, vals[2] * inv, vals[3] * inv);
    reinterpret_cast<float4*>(p)[64 + lane] =
        make_float4(vals[4] * inv, vals[5] * inv, vals[6] * inv, vals[7] * inv);
}

// ---------------- out = attn(512x512) @ V(512x64) per (b,h)
__global__ __launch_bounds__(256) void k_av(
    const float* __restrict__ A, const float* __restrict__ V,
    float* __restrict__ O)
{
    const int bh = blockIdx.y;
    const int n0 = blockIdx.x * 64;
    __shared__ float As[32][68];
    __shared__ float Vs[32][68];
    const float* Ap = A + (size_t)bh * 512 * 512;
    const float* Vp = V + (size_t)bh * 512 * 64;
    const int t = threadIdx.x;
    const int tx = t & 15, ty = t >> 4;
    float acc[4][4] = {};
    for (int k0 = 0; k0 < 512; k0 += 32) {
#pragma unroll
        for (int u = 0; u < 2; ++u) {
            const int f = t + u * 256;
            const int row = f >> 3;
            const int kk = (f & 7) * 4;
            float4 a = *reinterpret_cast<const float4*>(&Ap[(size_t)(n0 + row) * 512 + k0 + kk]);
            As[kk + 0][row] = a.x; As[kk + 1][row] = a.y;
            As[kk + 2][row] = a.z; As[kk + 3][row] = a.w;
            const int vrow = f >> 4;
            const int vcol = (f & 15) * 4;
            *reinterpret_cast<float4*>(&Vs[vrow][vcol]) =
                *reinterpret_cast<const float4*>(&Vp[(size_t)(k0 + vrow) * 64 + vcol]);
        }
        __syncthreads();
#pragma unroll
        for (int k = 0; k < 32; ++k) {
            float4 av  = *reinterpret_cast<const float4*>(&As[k][ty * 4]);
            float4 bv4 = *reinterpret_cast<const float4*>(&Vs[k][tx * 4]);
            float aa[4] = {av.x, av.y, av.z, av.w};
            float bb[4] = {bv4.x, bv4.y, bv4.z, bv4.w};
#pragma unroll
            for (int i = 0; i < 4; ++i)
#pragma unroll
                for (int j = 0; j < 4; ++j)
                    acc[i][j] = fmaf(aa[i], bb[j], acc[i][j]);
        }
        __syncthreads();
    }
#pragma unroll
    for (int i = 0; i < 4; ++i) {
        float4 o = make_float4(acc[i][0], acc[i][1], acc[i][2], acc[i][3]);
        *reinterpret_cast<float4*>(&O[(size_t)bh * 512 * 64 + (size_t)(n0 + ty * 4 + i) * 64 + tx * 4]) = o;
    }
}

// ---------------- out-proj: gather O(B,H,N,DH) rows -> @ Wh + bh + query -> P(B,N,D)
__global__ __launch_bounds__(256) void k_out(
    const float* __restrict__ O, const float* __restrict__ W,
    const float* __restrict__ bias, const float* __restrict__ X,
    float* __restrict__ P)
{
    const int m0 = blockIdx.x * 64;
    const int n0 = blockIdx.y * 64;
    __shared__ float As[16][68];
    __shared__ float Bs[16][68];
    const int t = threadIdx.x;
    const int tx = t & 15, ty = t >> 4;
    const int arow = t >> 2;
    const int akk  = (t & 3) * 4;
    const int bkk  = t >> 4;
    const int bcol = (t & 15) * 4;
    const int r_ = m0 + arow;
    const int bb_ = r_ >> 9;
    const int nn_ = r_ & 511;
    float acc[4][4] = {};
    for (int k0 = 0; k0 < 512; k0 += 16) {
        const int k = k0 + akk;
        const int h = k >> 6;
        const int dh = k & 63;
        float4 a = *reinterpret_cast<const float4*>(&O[(size_t)((bb_ * 8 + h) * 512 + nn_) * 64 + dh]);
        As[akk + 0][arow] = a.x; As[akk + 1][arow] = a.y;
        As[akk + 2][arow] = a.z; As[akk + 3][arow] = a.w;
        *reinterpret_cast<float4*>(&Bs[bkk][bcol]) =
            *reinterpret_cast<const float4*>(&W[(size_t)(k0 + bkk) * 512 + n0 + bcol]);
        __syncthreads();
#pragma unroll
        for (int k2 = 0; k2 < 16; ++k2) {
            float4 av  = *reinterpret_cast<const float4*>(&As[k2][ty * 4]);
            float4 bv4 = *reinterpret_cast<const float4*>(&Bs[k2][tx * 4]);
            float aa[4] = {av.x, av.y, av.z, av.w};
            float bb[4] = {bv4.x, bv4.y, bv4.z, bv4.w};
#pragma unroll
            for (int i = 0; i < 4; ++i)
#pragma unroll
                for (int j = 0; j < 4; ++j)
                    acc[i][j] = fmaf(aa[i], bb[j], acc[i][j]);
        }
        __syncthreads();
    }
    const int c0 = n0 + tx * 4;
    const float4 bb4 = *reinterpret_cast<const float4*>(&bias[c0]);
#pragma unroll
    for (int i = 0; i < 4; ++i) {
        const int r = m0 + ty * 4 + i;
        const float4 q4 = *reinterpret_cast<const float4*>(&X[(size_t)r * 512 + c0]);
        float4 o = make_float4(acc[i][0] + bb4.x + q4.x, acc[i][1] + bb4.y + q4.y,
                               acc[i][2] + bb4.z + q4.z, acc[i][3] + bb4.w + q4.w);
        *reinterpret_cast<float4*>(&P[(size_t)r * 512 + c0]) = o;
    }
}

// ---------------- final LayerNorm over D=512
__global__ __launch_bounds__(256) void k_ln(
    const float* __restrict__ P, const float* __restrict__ g,
    const float* __restrict__ be, float* __restrict__ out)
{
    const int row = blockIdx.x * 4 + (threadIdx.x >> 6);
    const int lane = threadIdx.x & 63;
    const float* p = P + (size_t)row * 512;
    float4 v0 = reinterpret_cast<const float4*>(p)[lane];
    float4 v1 = reinterpret_cast<const float4*>(p)[64 + lane];
    float s = v0.x + v0.y + v0.z + v0.w + v1.x + v1.y + v1.z + v1.w;
#pragma unroll
    for (int o = 32; o; o >>= 1) s += __shfl_xor(s, o);
    const float mean = s * (1.0f / 512.0f);
    float d[8] = {v0.x - mean, v0.y - mean, v0.z - mean, v0.w - mean,
                  v1.x - mean, v1.y - mean, v1.z - mean, v1.w - mean};
    float s2 = 0.f;
#pragma unroll
    for (int j = 0; j < 8; ++j) s2 += d[j] * d[j];
#pragma unroll
    for (int o = 32; o; o >>= 1) s2 += __shfl_xor(s2, o);
    const float rstd = rsqrtf(s2 * (1.0f / 512.0f) + 1e-7f);
    float4 g0 = reinterpret_cast<const float4*>(g)[lane];
    float4 g1 = reinterpret_cast<const float4*>(g)[64 + lane];
    float4 b0 = reinterpret_cast<const float4*>(be)[lane];
    float4 b1 = reinterpret_cast<const float4*>(be)[64 + lane];
    float* op = out + (size_t)row * 512;
    reinterpret_cast<float4*>(op)[lane] =
        make_float4(d[0] * rstd * g0.x + b0.x, d[1] * rstd * g0.y + b0.y,
                    d[2] * rstd * g0.z + b0.z, d[3] * rstd * g0.w + b0.w);
    reinterpret_cast<float4*>(op)[64 + lane] =
        make_float4(d[4] * rstd * g1.x + b1.x, d[5] * rstd * g1.y + b1.y,
                    d[6] * rstd * g1.z + b1.z, d[7] * rstd * g1.w + b1.w);
}

extern "C" void kernel_launch(void* const* d_in, const int* in_sizes, int n_in,
                              void* d_out, int out_size, void* d_ws, size_t ws_size,
                              hipStream_t stream)
{
    const float* query = (const float*)d_in[0];
    const int*   VL    = (const int*)d_in[1];
    const float* Wq = (const float*)d_in[2];  const float* bq = (const float*)d_in[3];
    const float* Wk = (const float*)d_in[4];  const float* bk = (const float*)d_in[5];
    const float* Wv = (const float*)d_in[6];  const float* bv = (const float*)d_in[7];
    const float* Wh = (const float*)d_in[8];  const float* bh = (const float*)d_in[9];
    const float* pos_k = (const float*)d_in[10];
    const float* c1w = (const float*)d_in[11]; const float* c1b = (const float*)d_in[12];
    const float* n1g = (const float*)d_in[13]; const float* n1b = (const float*)d_in[14];
    const float* c2w = (const float*)d_in[15]; const float* c2b = (const float*)d_in[16];
    const float* lng = (const float*)d_in[17]; const float* lnb = (const float*)d_in[18];

    float* ws = (float*)d_ws;
    const size_t M1 = (size_t)1 << 20;   // 1M floats
    // Layout (peak ~34M floats + tails):
    //   [0,2M)    Qb  (later O)          } overlapped by Y1 (bf16 channel-last,
    //   [2M,4M)   Kb  (later P)          }   32M u16 = [0,16M) floats),
    //   [4M,8M)   QP                     }   live conv1..conv2 only
    //   [16M,18M) Vb    (live qkv..av)
    //   [18M,34M) S1    scores / attn
    //   [34M,+256) ST; +256 ST2; +512 Wf1/Wf2 (u16)
    float* Qb = ws;
    float* Kb = ws + 2 * M1;
    float* QP = ws + 4 * M1;
    u16*   Y1 = (u16*)ws;                        // (B,512,512,16) bf16
    float* Vb = ws + 16 * M1;
    float* S1 = ws + 18 * M1;
    float* ST = ws + 34 * M1;
    float* ST2 = ST + 256;
    u16*   Wf1 = (u16*)(ST + 512);
    u16*   Wf2 = Wf1 + 3584;
    float* O = Qb;
    float* P = Kb;

    hipMemsetAsync(ST, 0, 256 * sizeof(float), stream);

    k_wprep<<<1, 256, 0, stream>>>(c1w, c2w, Wf1, Wf2);
    k_qkv<<<dim3(64, 8, 3), 256, 0, stream>>>(query, Wq, bq, Wk, bk, Wv, bv, Qb, Kb, Vb);
    k_qpos<<<1024, 256, 0, stream>>>(Qb, pos_k, QP);
    k_scores<<<dim3(8, 8, 64), 256, 0, stream>>>(Qb, Kb, QP, S1);
    k_conv1m<<<dim3(16, 16, 8), 256, 0, stream>>>(S1, Wf1, c1b, Y1, VL, ST);
    k_statfin<<<1, 128, 0, stream>>>(ST, VL, n1g, n1b, ST2);
    k_conv2m<<<dim3(16, 16, 8), 256, 0, stream>>>(Y1, ST2, Wf2, c2b, S1);
    k_softmax<<<8192, 256, 0, stream>>>(S1, VL);
    k_av<<<dim3(8, 64), 256, 0, stream>>>(S1, Vb, O);
    k_out<<<dim3(64, 8), 256, 0, stream>>>(O, Wh, bh, query, P);
    k_ln<<<1024, 256, 0, stream>>>(P, lng, lnb, (float*)d_out);
}

// Round 4
// 286.488 us; speedup vs baseline: 2.7828x; 1.5792x over previous
//
#include <hip/hip_runtime.h>

#define PC_ 60

typedef unsigned short u16;
typedef __attribute__((ext_vector_type(8))) short short8v;   // 8 bf16 (4 VGPR)
typedef __attribute__((ext_vector_type(4))) float f32x4;

__device__ inline float bf2f(u16 u) {
    union { unsigned int i; float f; } x; x.i = ((unsigned)u) << 16; return x.f;
}
__device__ inline u16 f2bf(float f) {
    union { float f; unsigned int i; } x; x.f = f;
    unsigned int r = x.i + 0x7fff + ((x.i >> 16) & 1);   // RNE
    return (u16)(r >> 16);
}
__device__ inline unsigned pk2(float a, float b) {
    return (unsigned)f2bf(a) | ((unsigned)f2bf(b) << 16);
}

// ---------------- prep: query f32 -> bf16
__global__ __launch_bounds__(256) void k_prepx(const float* __restrict__ X, u16* __restrict__ Xb)
{
    const int i = (blockIdx.x * 256 + threadIdx.x) * 8;
    float4 a = *reinterpret_cast<const float4*>(X + i);
    float4 b = *reinterpret_cast<const float4*>(X + i + 4);
    *reinterpret_cast<uint4*>(Xb + i) =
        make_uint4(pk2(a.x, a.y), pk2(a.z, a.w), pk2(b.x, b.y), pk2(b.z, b.w));
}

// ---------------- prep: W (512x512, k-major) -> W^T bf16 (n-major)
__global__ __launch_bounds__(256) void k_prept(
    const float* __restrict__ W0, const float* __restrict__ W1,
    const float* __restrict__ W2, const float* __restrict__ W3,
    u16* __restrict__ T0, u16* __restrict__ T1, u16* __restrict__ T2, u16* __restrict__ T3)
{
    const int z = blockIdx.z;
    const float* W = (z == 0) ? W0 : (z == 1) ? W1 : (z == 2) ? W2 : W3;
    u16* T        = (z == 0) ? T0 : (z == 1) ? T1 : (z == 2) ? T2 : T3;
    __shared__ float ls[64 * 65];
    const int k0 = blockIdx.x * 64, n0 = blockIdx.y * 64;
    const int t = threadIdx.x;
#pragma unroll
    for (int i = 0; i < 16; ++i) {
        const int idx = t + i * 256, r = idx >> 6, c = idx & 63;
        ls[c * 65 + r] = W[(size_t)(k0 + r) * 512 + n0 + c];
    }
    __syncthreads();
#pragma unroll
    for (int i = 0; i < 16; ++i) {
        const int idx = t + i * 256, r = idx >> 6, c = idx & 63;
        T[(size_t)(n0 + r) * 512 + k0 + c] = f2bf(ls[r * 65 + c]);
    }
}

// ---------------- prep: conv weight fragments + pos_k bf16
__global__ void k_wprep(const float* __restrict__ c1w, const float* __restrict__ c2w,
                        const float* __restrict__ pos_k,
                        u16* __restrict__ Wf1, u16* __restrict__ Wf2, u16* __restrict__ pos_kb)
{
    const int t = threadIdx.x;
    for (int s = t; s < 448; s += 256) {
        const int q = s >> 6, l = s & 63, lg = l >> 4, n = l & 15;
        const int G = q * 4 + lg;
        unsigned o[4];
#pragma unroll
        for (int u2 = 0; u2 < 4; ++u2) {
            float v0 = 0.f, v1 = 0.f;
            if (G < 25) {
                const int dn = G / 5, dm = G - dn * 5;
                v0 = c1w[((dn * 5 + dm) * 8 + u2 * 2 + 0) * 16 + n];
                v1 = c1w[((dn * 5 + dm) * 8 + u2 * 2 + 1) * 16 + n];
            }
            o[u2] = pk2(v0, v1);
        }
        *reinterpret_cast<uint4*>(&Wf1[s * 8]) = make_uint4(o[0], o[1], o[2], o[3]);
    }
    for (int s = t; s < 832; s += 256) {
        const int q = s >> 6, l = s & 63, lg = l >> 4, n = l & 15;
        const int G = q * 4 + lg;
        unsigned o[4];
#pragma unroll
        for (int u2 = 0; u2 < 4; ++u2) {
            float v0 = 0.f, v1 = 0.f;
            if (G < 50 && n < 8) {
                const int pos = G >> 1, h = G & 1;
                const int dn = pos / 5, dm = pos - dn * 5;
                v0 = c2w[((dn * 5 + dm) * 16 + h * 8 + u2 * 2 + 0) * 8 + n];
                v1 = c2w[((dn * 5 + dm) * 16 + h * 8 + u2 * 2 + 1) * 8 + n];
            }
            o[u2] = pk2(v0, v1);
        }
        *reinterpret_cast<uint4*>(&Wf2[s * 8]) = make_uint4(o[0], o[1], o[2], o[3]);
    }
    for (int s = t; s < 128 * 64; s += 256) {
        const int r = s >> 6;
        pos_kb[s] = (r < 121) ? f2bf(pos_k[s]) : (u16)0;
    }
}

// ---------------- QKV (MFMA): Xb(4096x512)bf16 @ WT -> Q/K bf16 (B,H,N,DH), V^T bf16 (B,H,DH,N)
__global__ __launch_bounds__(256) void k_qkvm(
    const u16* __restrict__ Xb,
    const u16* __restrict__ WT0, const u16* __restrict__ WT1, const u16* __restrict__ WT2,
    const float* __restrict__ b0, const float* __restrict__ b1, const float* __restrict__ b2,
    u16* __restrict__ Qb, u16* __restrict__ Kb, u16* __restrict__ Vt)
{
    const int z = blockIdx.z;
    const u16* WT    = (z == 0) ? WT0 : (z == 1) ? WT1 : WT2;
    const float* bias = (z == 0) ? b0 : (z == 1) ? b1 : b2;
    __shared__ __align__(16) u16 sh[18432];          // As 128x72, Bs 128x72
    u16* As = sh; u16* Bs = sh + 9216;
    const int t = threadIdx.x, lane = t & 63, wave = t >> 6;
    const int wm = wave >> 1, wn = wave & 1;
    const int lg = lane >> 4, ln16 = lane & 15;
    const int m0 = blockIdx.x * 128, n0 = blockIdx.y * 128;
    f32x4 acc[4][4] = {};
    for (int k0 = 0; k0 < 512; k0 += 64) {
#pragma unroll
        for (int u = 0; u < 4; ++u) {
            const int chunk = u * 256 + t, row = chunk >> 3, ko = (chunk & 7) * 8;
            *reinterpret_cast<uint4*>(As + row * 72 + ko) =
                *reinterpret_cast<const uint4*>(Xb + (size_t)(m0 + row) * 512 + k0 + ko);
            *reinterpret_cast<uint4*>(Bs + row * 72 + ko) =
                *reinterpret_cast<const uint4*>(WT + (size_t)(n0 + row) * 512 + k0 + ko);
        }
        __syncthreads();
#pragma unroll
        for (int kk = 0; kk < 64; kk += 32) {
            short8v a[4], bfr[4];
#pragma unroll
            for (int mi = 0; mi < 4; ++mi)
                a[mi] = *reinterpret_cast<const short8v*>(As + (wm * 64 + mi * 16 + ln16) * 72 + kk + lg * 8);
#pragma unroll
            for (int ni = 0; ni < 4; ++ni)
                bfr[ni] = *reinterpret_cast<const short8v*>(Bs + (wn * 64 + ni * 16 + ln16) * 72 + kk + lg * 8);
#pragma unroll
            for (int mi = 0; mi < 4; ++mi)
#pragma unroll
                for (int ni = 0; ni < 4; ++ni)
                    acc[mi][ni] = __builtin_amdgcn_mfma_f32_16x16x32_bf16(a[mi], bfr[ni], acc[mi][ni], 0, 0, 0);
        }
        __syncthreads();
    }
    u16* Cs = sh + wave * 4608;                       // 64x72 per wave
#pragma unroll
    for (int ni = 0; ni < 4; ++ni) {
        const float bv = bias[n0 + wn * 64 + ni * 16 + ln16];
#pragma unroll
        for (int mi = 0; mi < 4; ++mi)
#pragma unroll
            for (int r = 0; r < 4; ++r)
                Cs[(mi * 16 + lg * 4 + r) * 72 + ni * 16 + ln16] = f2bf(acc[mi][ni][r] + bv);
    }
    if (z < 2) {
        u16* O = (z == 0) ? Qb : Kb;
#pragma unroll
        for (int j = 0; j < 8; ++j) {
            const int chunk = j * 64 + lane, row = chunk >> 3, co = (chunk & 7) * 8;
            const int tok = m0 + wm * 64 + row;
            const int b = tok >> 9, n = tok & 511;
            const int cg = n0 + wn * 64 + co;
            const int h = cg >> 6, dh = cg & 63;
            *reinterpret_cast<uint4*>(O + ((size_t)((b * 8 + h) * 512 + n)) * 64 + dh) =
                *reinterpret_cast<const uint4*>(Cs + row * 72 + co);
        }
    } else {
#pragma unroll
        for (int j = 0; j < 8; ++j) {
            const int chunk = j * 64 + lane, dr = chunk >> 3, no8 = (chunk & 7) * 8;
            const int cg = n0 + wn * 64 + dr;
            const int h = cg >> 6, dh = cg & 63;
            const int tok = m0 + wm * 64 + no8;
            const int b = tok >> 9, n = tok & 511;
            u16 v[8];
#pragma unroll
            for (int e = 0; e < 8; ++e) v[e] = Cs[(no8 + e) * 72 + dr];
            uint4 o = make_uint4((unsigned)v[0] | ((unsigned)v[1] << 16),
                                 (unsigned)v[2] | ((unsigned)v[3] << 16),
                                 (unsigned)v[4] | ((unsigned)v[5] << 16),
                                 (unsigned)v[6] | ((unsigned)v[7] << 16));
            *reinterpret_cast<uint4*>(Vt + ((size_t)((b * 8 + h) * 64 + dh)) * 512 + n) = o;
        }
    }
}

// ---------------- qp (MFMA): Q(bh,n,64) @ pos_k^T -> QP bf16 (bh,n,128pad)
__global__ __launch_bounds__(256) void k_qposm(
    const u16* __restrict__ Qb, const u16* __restrict__ pos_kb, u16* __restrict__ QP)
{
    __shared__ __align__(16) u16 sh[18432];
    u16* As = sh; u16* Bs = sh + 9216;
    const int t = threadIdx.x, lane = t & 63, wave = t >> 6;
    const int lg = lane >> 4, ln16 = lane & 15;
    const int n0 = blockIdx.x * 128, bh = blockIdx.y;
#pragma unroll
    for (int u = 0; u < 4; ++u) {
        const int chunk = u * 256 + t, row = chunk >> 3, ko = (chunk & 7) * 8;
        *reinterpret_cast<uint4*>(As + row * 72 + ko) =
            *reinterpret_cast<const uint4*>(Qb + ((size_t)(bh * 512 + n0 + row)) * 64 + ko);
        *reinterpret_cast<uint4*>(Bs + row * 72 + ko) =
            *reinterpret_cast<const uint4*>(pos_kb + (size_t)row * 64 + ko);
    }
    __syncthreads();
    f32x4 acc[2][8] = {};
#pragma unroll
    for (int kk = 0; kk < 64; kk += 32) {
        short8v a[2], bfr[8];
#pragma unroll
        for (int mi = 0; mi < 2; ++mi)
            a[mi] = *reinterpret_cast<const short8v*>(As + (wave * 32 + mi * 16 + ln16) * 72 + kk + lg * 8);
#pragma unroll
        for (int ni = 0; ni < 8; ++ni)
            bfr[ni] = *reinterpret_cast<const short8v*>(Bs + (ni * 16 + ln16) * 72 + kk + lg * 8);
#pragma unroll
        for (int mi = 0; mi < 2; ++mi)
#pragma unroll
            for (int ni = 0; ni < 8; ++ni)
                acc[mi][ni] = __builtin_amdgcn_mfma_f32_16x16x32_bf16(a[mi], bfr[ni], acc[mi][ni], 0, 0, 0);
    }
    __syncthreads();
    u16* Cs = sh + wave * 4352;                      // 32x136 per wave
#pragma unroll
    for (int mi = 0; mi < 2; ++mi)
#pragma unroll
        for (int ni = 0; ni < 8; ++ni)
#pragma unroll
            for (int r = 0; r < 4; ++r)
                Cs[(mi * 16 + lg * 4 + r) * 136 + ni * 16 + ln16] = f2bf(acc[mi][ni][r]);
#pragma unroll
    for (int j = 0; j < 8; ++j) {
        const int chunk = j * 64 + lane, row = chunk >> 4, co = (chunk & 15) * 8;
        *reinterpret_cast<uint4*>(QP + ((size_t)(bh * 512 + n0 + wave * 32 + row)) * 128 + co) =
            *reinterpret_cast<const uint4*>(Cs + row * 136 + co);
    }
}

// ---------------- scores (MFMA): (Q@K^T + QP[rel]) / 8 -> S bf16 (bh,n,m)
__global__ __launch_bounds__(256) void k_scoresm(
    const u16* __restrict__ Qb, const u16* __restrict__ Kb, const u16* __restrict__ QP,
    u16* __restrict__ S)
{
    __shared__ __align__(16) u16 sh[18432];
    u16* As = sh; u16* Bs = sh + 9216;
    const int t = threadIdx.x, lane = t & 63, wave = t >> 6;
    const int wm = wave >> 1, wn = wave & 1;
    const int lg = lane >> 4, ln16 = lane & 15;
    const int m0 = blockIdx.x * 128, n0 = blockIdx.y * 128, bh = blockIdx.z;
#pragma unroll
    for (int u = 0; u < 4; ++u) {
        const int chunk = u * 256 + t, row = chunk >> 3, ko = (chunk & 7) * 8;
        *reinterpret_cast<uint4*>(As + row * 72 + ko) =
            *reinterpret_cast<const uint4*>(Qb + ((size_t)(bh * 512 + n0 + row)) * 64 + ko);
        *reinterpret_cast<uint4*>(Bs + row * 72 + ko) =
            *reinterpret_cast<const uint4*>(Kb + ((size_t)(bh * 512 + m0 + row)) * 64 + ko);
    }
    __syncthreads();
    f32x4 acc[4][4] = {};
#pragma unroll
    for (int kk = 0; kk < 64; kk += 32) {
        short8v a[4], bfr[4];
#pragma unroll
        for (int mi = 0; mi < 4; ++mi)
            a[mi] = *reinterpret_cast<const short8v*>(As + (wm * 64 + mi * 16 + ln16) * 72 + kk + lg * 8);
#pragma unroll
        for (int ni = 0; ni < 4; ++ni)
            bfr[ni] = *reinterpret_cast<const short8v*>(Bs + (wn * 64 + ni * 16 + ln16) * 72 + kk + lg * 8);
#pragma unroll
        for (int mi = 0; mi < 4; ++mi)
#pragma unroll
            for (int ni = 0; ni < 4; ++ni)
                acc[mi][ni] = __builtin_amdgcn_mfma_f32_16x16x32_bf16(a[mi], bfr[ni], acc[mi][ni], 0, 0, 0);
    }
    __syncthreads();
    u16* QPs = sh;                                   // 128x128 bf16
#pragma unroll
    for (int u = 0; u < 8; ++u) {
        const int chunk = u * 256 + t, row = chunk >> 4, co = (chunk & 15) * 8;
        *reinterpret_cast<uint4*>(QPs + row * 128 + co) =
            *reinterpret_cast<const uint4*>(QP + ((size_t)(bh * 512 + n0 + row)) * 128 + co);
    }
    __syncthreads();
#pragma unroll
    for (int mi = 0; mi < 4; ++mi)
#pragma unroll
        for (int ni = 0; ni < 4; ++ni) {
            const int m_g = m0 + wn * 64 + ni * 16 + ln16;
#pragma unroll
            for (int r = 0; r < 4; ++r) {
                const int n_loc = wm * 64 + mi * 16 + lg * 4 + r;
                const int n_g = n0 + n_loc;
                int rel = m_g - n_g;
                rel = rel < -PC_ ? -PC_ : (rel > PC_ ? PC_ : rel);
                const float v = (acc[mi][ni][r] + bf2f(QPs[n_loc * 128 + rel + PC_])) * 0.125f;
                S[(size_t)bh * 262144 + (size_t)n_g * 512 + m_g] = f2bf(v);
            }
        }
}

// ---------------- conv1 (MFMA): S bf16 planar -> Y(B,512,512,16) bf16 ch-last + fused stats
__global__ __launch_bounds__(256) void k_conv1m(
    const u16* __restrict__ S, const u16* __restrict__ Wf,
    const float* __restrict__ bias, u16* __restrict__ Y,
    const int* __restrict__ VL, float* __restrict__ ST)
{
    __shared__ __align__(16) u16 xs[10368];
    __shared__ float wred[4][16][2];
    const int t = threadIdx.x;
    const int b = blockIdx.z;
    const int n0 = blockIdx.y * 32;
    const int m0 = blockIdx.x * 32;
    const u16* sp0 = S + (size_t)(b * 8) * 262144;
    for (int idx = t; idx < 1296; idx += 256) {
        const int r = idx / 36; const int c = idx - r * 36;
        const int gn = n0 - 2 + r, gm = m0 - 2 + c;
        uint4 pk = make_uint4(0, 0, 0, 0);
        if ((unsigned)gn < 512u && (unsigned)gm < 512u) {
            const u16* p = sp0 + (size_t)gn * 512 + gm;
            u16 v[8];
#pragma unroll
            for (int e = 0; e < 8; ++e) v[e] = p[(size_t)e * 262144];
            pk.x = (unsigned)v[0] | ((unsigned)v[1] << 16);
            pk.y = (unsigned)v[2] | ((unsigned)v[3] << 16);
            pk.z = (unsigned)v[4] | ((unsigned)v[5] << 16);
            pk.w = (unsigned)v[6] | ((unsigned)v[7] << 16);
        }
        *reinterpret_cast<uint4*>(&xs[idx * 8]) = pk;
    }
    const int lane = t & 63, wave = t >> 6;
    const int lg = lane >> 4, ln16 = lane & 15;
    short8v bq[7];
#pragma unroll
    for (int q = 0; q < 7; ++q)
        bq[q] = *reinterpret_cast<const short8v*>(&Wf[(q * 64 + lane) * 8]);
    int aoff[7];
#pragma unroll
    for (int q = 0; q < 7; ++q) {
        const int G = q * 4 + lg; const int p = (G < 25) ? G : 0;
        const int dn = p / 5, dm = p - dn * 5;
        aoff[q] = (dn * 36 + dm) * 8;
    }
    const float bs = bias[ln16];
    const int vl = VL[b];
    float sst = 0.f, sst2 = 0.f;
    __syncthreads();
    for (int i = 0; i < 16; ++i) {
        const int j = wave * 16 + i;
        const int tr = j >> 1, c0 = (j & 1) << 4;
        const int pb = (tr * 36 + c0 + ln16) * 8;
        f32x4 acc = {bs, bs, bs, bs};
#pragma unroll
        for (int q = 0; q < 7; ++q) {
            short8v a = *reinterpret_cast<const short8v*>(&xs[pb + aoff[q]]);
            acc = __builtin_amdgcn_mfma_f32_16x16x32_bf16(a, bq[q], acc, 0, 0, 0);
        }
        u16* yp = Y + (((size_t)(b * 512 + n0 + tr)) * 512 + (m0 + c0 + lg * 4)) * 16 + ln16;
        yp[0]  = f2bf(acc[0]); yp[16] = f2bf(acc[1]);
        yp[32] = f2bf(acc[2]); yp[48] = f2bf(acc[3]);
        if (n0 + tr < vl) {
            sst  += acc[0] + acc[1] + acc[2] + acc[3];
            sst2 += acc[0]*acc[0] + acc[1]*acc[1] + acc[2]*acc[2] + acc[3]*acc[3];
        }
    }
    sst  += __shfl_xor(sst, 16);  sst  += __shfl_xor(sst, 32);
    sst2 += __shfl_xor(sst2, 16); sst2 += __shfl_xor(sst2, 32);
    if (lane < 16) { wred[wave][lane][0] = sst; wred[wave][lane][1] = sst2; }
    __syncthreads();
    if (t < 16) {
        const float a  = wred[0][t][0] + wred[1][t][0] + wred[2][t][0] + wred[3][t][0];
        const float b2 = wred[0][t][1] + wred[1][t][1] + wred[2][t][1] + wred[3][t][1];
        atomicAdd(&ST[(b * 16 + t) * 2 + 0], a);
        atomicAdd(&ST[(b * 16 + t) * 2 + 1], b2);
    }
}

__global__ void k_statfin(const float* __restrict__ ST, const int* __restrict__ VL,
                          const float* __restrict__ g, const float* __restrict__ be,
                          float* __restrict__ ST2)
{
    const int i = threadIdx.x;
    if (i < 128) {
        const int b = i >> 4, c = i & 15;
        const float sw = (float)VL[b] * 512.f;
        const float mean = ST[i * 2] / sw;
        const float var = ST[i * 2 + 1] / sw - mean * mean;
        const float scale = g[c] * rsqrtf(var + 1e-7f);
        ST2[i * 2] = scale;
        ST2[i * 2 + 1] = be[c] - mean * scale;
    }
}

// ---------------- conv2 (MFMA): Y ch-last bf16, norm+relu fused -> S2 bf16 planar
__global__ __launch_bounds__(256) void k_conv2m(
    const u16* __restrict__ Y, const float* __restrict__ ST2,
    const u16* __restrict__ Wf, const float* __restrict__ bias,
    u16* __restrict__ S2)
{
    __shared__ __align__(16) u16 xs[20736];
    const int t = threadIdx.x;
    const int b = blockIdx.z;
    const int n0 = blockIdx.y * 32, m0 = blockIdx.x * 32;
    float sc[16], shv[16];
#pragma unroll
    for (int ch = 0; ch < 16; ++ch) {
        sc[ch]  = ST2[(b * 16 + ch) * 2 + 0];
        shv[ch] = ST2[(b * 16 + ch) * 2 + 1];
    }
    for (int idx = t; idx < 1296; idx += 256) {
        const int r = idx / 36; const int c = idx - r * 36;
        const int gn = n0 - 2 + r, gm = m0 - 2 + c;
        uint4 p0 = make_uint4(0, 0, 0, 0), p1 = p0;
        if ((unsigned)gn < 512u && (unsigned)gm < 512u) {
            const u16* yp = Y + (((size_t)(b * 512 + gn)) * 512 + gm) * 16;
            const uint4 r0 = *reinterpret_cast<const uint4*>(yp);
            const uint4 r1 = *reinterpret_cast<const uint4*>(yp + 8);
            const unsigned w0[4] = {r0.x, r0.y, r0.z, r0.w};
            const unsigned w1[4] = {r1.x, r1.y, r1.z, r1.w};
            unsigned o0[4], o1[4];
#pragma unroll
            for (int u2 = 0; u2 < 4; ++u2) {
                const int ch = u2 * 2;
                float a0 = bf2f((u16)(w0[u2] & 0xffff));
                float a1 = bf2f((u16)(w0[u2] >> 16));
                a0 = fmaf(a0, sc[ch], shv[ch]);          a0 = a0 > 0.f ? a0 : 0.f;
                a1 = fmaf(a1, sc[ch + 1], shv[ch + 1]);  a1 = a1 > 0.f ? a1 : 0.f;
                o0[u2] = pk2(a0, a1);
                const int ch2 = 8 + u2 * 2;
                float b0 = bf2f((u16)(w1[u2] & 0xffff));
                float b1 = bf2f((u16)(w1[u2] >> 16));
                b0 = fmaf(b0, sc[ch2], shv[ch2]);          b0 = b0 > 0.f ? b0 : 0.f;
                b1 = fmaf(b1, sc[ch2 + 1], shv[ch2 + 1]);  b1 = b1 > 0.f ? b1 : 0.f;
                o1[u2] = pk2(b0, b1);
            }
            p0 = make_uint4(o0[0], o0[1], o0[2], o0[3]);
            p1 = make_uint4(o1[0], o1[1], o1[2], o1[3]);
        }
        *reinterpret_cast<uint4*>(&xs[idx * 8]) = p0;
        *reinterpret_cast<uint4*>(&xs[10368 + idx * 8]) = p1;
    }
    const int lane = t & 63, wave = t >> 6;
    const int lg = lane >> 4, ln16 = lane & 15;
    short8v bq[13];
#pragma unroll
    for (int q = 0; q < 13; ++q)
        bq[q] = *reinterpret_cast<const short8v*>(&Wf[(q * 64 + lane) * 8]);
    int aoff[13];
#pragma unroll
    for (int q = 0; q < 13; ++q) {
        const int G = q * 4 + lg; const int p = (G < 50) ? G : 0;
        const int pos = p >> 1, h = p & 1;
        const int dn = pos / 5, dm = pos - dn * 5;
        aoff[q] = h * 10368 + (dn * 36 + dm) * 8;
    }
    const float bs = (ln16 < 8) ? bias[ln16] : 0.f;
    __syncthreads();
    for (int i = 0; i < 16; ++i) {
        const int j = wave * 16 + i;
        const int tr = j >> 1, c0 = (j & 1) << 4;
        const int pb = (tr * 36 + c0 + ln16) * 8;
        f32x4 acc = {bs, bs, bs, bs};
#pragma unroll
        for (int q = 0; q < 13; ++q) {
            short8v a = *reinterpret_cast<const short8v*>(&xs[pb + aoff[q]]);
            acc = __builtin_amdgcn_mfma_f32_16x16x32_bf16(a, bq[q], acc, 0, 0, 0);
        }
        if (ln16 < 8) {
            uint2 o = make_uint2(pk2(acc[0], acc[1]), pk2(acc[2], acc[3]));
            *reinterpret_cast<uint2*>(
                &S2[(((size_t)(b * 8 + ln16)) * 512 + n0 + tr) * 512 + m0 + c0 + lg * 4]) = o;
        }
    }
}

// ---------------- masked softmax over m, bf16 in-place
__global__ __launch_bounds__(256) void k_softmax(u16* __restrict__ S,
                                                 const int* __restrict__ VL)
{
    const int row = blockIdx.x * 4 + (threadIdx.x >> 6);   // (b*8+h)*512 + n
    const int lane = threadIdx.x & 63;
    const int b = row >> 12;
    const int vl = VL[b];
    u16* p = S + (size_t)row * 512;
    uint4 v = *reinterpret_cast<const uint4*>(p + lane * 8);
    const unsigned w[4] = {v.x, v.y, v.z, v.w};
    float vals[8];
#pragma unroll
    for (int j = 0; j < 4; ++j) {
        vals[2 * j]     = bf2f((u16)(w[j] & 0xffff));
        vals[2 * j + 1] = bf2f((u16)(w[j] >> 16));
    }
    const int mbase = lane * 8;
    float mx = -3.0e38f;
#pragma unroll
    for (int j = 0; j < 8; ++j) {
        if (mbase + j >= vl) vals[j] = -3.0e38f;
        mx = fmaxf(mx, vals[j]);
    }
#pragma unroll
    for (int o = 32; o; o >>= 1) mx = fmaxf(mx, __shfl_xor(mx, o));
    float sum = 0.f;
#pragma unroll
    for (int j = 0; j < 8; ++j) {
        const float e = __expf(vals[j] - mx);
        vals[j] = e;
        sum += e;
    }
#pragma unroll
    for (int o = 32; o; o >>= 1) sum += __shfl_xor(sum, o);
    const float inv = 1.0f / sum;
    uint4 ov = make_uint4(pk2(vals[0] * inv, vals[1] * inv), pk2(vals[2] * inv, vals[3] * inv),
                          pk2(vals[4] * inv, vals[5] * inv), pk2(vals[6] * inv, vals[7] * inv));
    *reinterpret_cast<uint4*>(p + lane * 8) = ov;
}

// ---------------- av (MFMA): P(bh,n,m)bf16 @ V^T(bh,dh,m)bf16 -> X2(B,N,512)bf16
__global__ __launch_bounds__(256) void k_avm(
    const u16* __restrict__ P, const u16* __restrict__ Vt, u16* __restrict__ X2)
{
    __shared__ __align__(16) u16 sh[13824];          // As 128x72, Bs 64x72
    u16* As = sh; u16* Bs = sh + 9216;
    const int t = threadIdx.x, lane = t & 63, wave = t >> 6;
    const int lg = lane >> 4, ln16 = lane & 15;
    const int n0 = blockIdx.x * 128, bh = blockIdx.y;
    const int b = bh >> 3, h = bh & 7;
    f32x4 acc[2][4] = {};
    for (int k0 = 0; k0 < 512; k0 += 64) {
#pragma unroll
        for (int u = 0; u < 4; ++u) {
            const int chunk = u * 256 + t, row = chunk >> 3, ko = (chunk & 7) * 8;
            *reinterpret_cast<uint4*>(As + row * 72 + ko) =
                *reinterpret_cast<const uint4*>(P + ((size_t)(bh * 512 + n0 + row)) * 512 + k0 + ko);
        }
#pragma unroll
        for (int u = 0; u < 2; ++u) {
            const int chunk = u * 256 + t, row = chunk >> 3, ko = (chunk & 7) * 8;
            *reinterpret_cast<uint4*>(Bs + row * 72 + ko) =
                *reinterpret_cast<const uint4*>(Vt + ((size_t)(bh * 64 + row)) * 512 + k0 + ko);
        }
        __syncthreads();
#pragma unroll
        for (int kk = 0; kk < 64; kk += 32) {
            short8v a[2], bfr[4];
#pragma unroll
            for (int mi = 0; mi < 2; ++mi)
                a[mi] = *reinterpret_cast<const short8v*>(As + (wave * 32 + mi * 16 + ln16) * 72 + kk + lg * 8);
#pragma unroll
            for (int ni = 0; ni < 4; ++ni)
                bfr[ni] = *reinterpret_cast<const short8v*>(Bs + (ni * 16 + ln16) * 72 + kk + lg * 8);
#pragma unroll
            for (int mi = 0; mi < 2; ++mi)
#pragma unroll
                for (int ni = 0; ni < 4; ++ni)
                    acc[mi][ni] = __builtin_amdgcn_mfma_f32_16x16x32_bf16(a[mi], bfr[ni], acc[mi][ni], 0, 0, 0);
        }
        __syncthreads();
    }
    u16* Cs = sh + wave * 2304;                      // 32x72 per wave
#pragma unroll
    for (int mi = 0; mi < 2; ++mi)
#pragma unroll
        for (int ni = 0; ni < 4; ++ni)
#pragma unroll
            for (int r = 0; r < 4; ++r)
                Cs[(mi * 16 + lg * 4 + r) * 72 + ni * 16 + ln16] = f2bf(acc[mi][ni][r]);
#pragma unroll
    for (int j = 0; j < 4; ++j) {
        const int chunk = j * 64 + lane, row = chunk >> 3, co = (chunk & 7) * 8;
        const int tn = n0 + wave * 32 + row;
        *reinterpret_cast<uint4*>(X2 + ((size_t)(b * 512 + tn)) * 512 + h * 64 + co) =
            *reinterpret_cast<const uint4*>(Cs + row * 72 + co);
    }
}

// ---------------- out-proj (MFMA): X2 @ WhT + bh + query -> P f32
__global__ __launch_bounds__(256) void k_outm(
    const u16* __restrict__ X2, const u16* __restrict__ WT, const float* __restrict__ bias,
    const float* __restrict__ Xq, float* __restrict__ Pout)
{
    __shared__ __align__(16) u16 sh[18432];
    u16* As = sh; u16* Bs = sh + 9216;
    const int t = threadIdx.x, lane = t & 63, wave = t >> 6;
    const int wm = wave >> 1, wn = wave & 1;
    const int lg = lane >> 4, ln16 = lane & 15;
    const int m0 = blockIdx.x * 128, n0 = blockIdx.y * 128;
    f32x4 acc[4][4] = {};
    for (int k0 = 0; k0 < 512; k0 += 64) {
#pragma unroll
        for (int u = 0; u < 4; ++u) {
            const int chunk = u * 256 + t, row = chunk >> 3, ko = (chunk & 7) * 8;
            *reinterpret_cast<uint4*>(As + row * 72 + ko) =
                *reinterpret_cast<const uint4*>(X2 + (size_t)(m0 + row) * 512 + k0 + ko);
            *reinterpret_cast<uint4*>(Bs + row * 72 + ko) =
                *reinterpret_cast<const uint4*>(WT + (size_t)(n0 + row) * 512 + k0 + ko);
        }
        __syncthreads();
#pragma unroll
        for (int kk = 0; kk < 64; kk += 32) {
            short8v a[4], bfr[4];
#pragma unroll
            for (int mi = 0; mi < 4; ++mi)
                a[mi] = *reinterpret_cast<const short8v*>(As + (wm * 64 + mi * 16 + ln16) * 72 + kk + lg * 8);
#pragma unroll
            for (int ni = 0; ni < 4; ++ni)
                bfr[ni] = *reinterpret_cast<const short8v*>(Bs + (wn * 64 + ni * 16 + ln16) * 72 + kk + lg * 8);
#pragma unroll
            for (int mi = 0; mi < 4; ++mi)
#pragma unroll
                for (int ni = 0; ni < 4; ++ni)
                    acc[mi][ni] = __builtin_amdgcn_mfma_f32_16x16x32_bf16(a[mi], bfr[ni], acc[mi][ni], 0, 0, 0);
        }
        __syncthreads();
    }
#pragma unroll
    for (int ni = 0; ni < 4; ++ni) {
        const int cg = n0 + wn * 64 + ni * 16 + ln16;
        const float bv = bias[cg];
#pragma unroll
        for (int mi = 0; mi < 4; ++mi)
#pragma unroll
            for (int r = 0; r < 4; ++r) {
                const int tok = m0 + wm * 64 + mi * 16 + lg * 4 + r;
                Pout[(size_t)tok * 512 + cg] = acc[mi][ni][r] + bv + Xq[(size_t)tok * 512 + cg];
            }
    }
}

// ---------------- final LayerNorm over D=512
__global__ __launch_bounds__(256) void k_ln(
    const float* __restrict__ P, const float* __restrict__ g,
    const float* __restrict__ be, float* __restrict__ out)
{
    const int row = blockIdx.x * 4 + (threadIdx.x >> 6);
    const int lane = threadIdx.x & 63;
    const float* p = P + (size_t)row * 512;
    float4 v0 = reinterpret_cast<const float4*>(p)[lane];
    float4 v1 = reinterpret_cast<const float4*>(p)[64 + lane];
    float s = v0.x + v0.y + v0.z + v0.w + v1.x + v1.y + v1.z + v1.w;
#pragma unroll
    for (int o = 32; o; o >>= 1) s += __shfl_xor(s, o);
    const float mean = s * (1.0f / 512.0f);
    float d[8] = {v0.x - mean, v0.y - mean, v0.z - mean, v0.w - mean,
                  v1.x - mean, v1.y - mean, v1.z - mean, v1.w - mean};
    float s2 = 0.f;
#pragma unroll
    for (int j = 0; j < 8; ++j) s2 += d[j] * d[j];
#pragma unroll
    for (int o = 32; o; o >>= 1) s2 += __shfl_xor(s2, o);
    const float rstd = rsqrtf(s2 * (1.0f / 512.0f) + 1e-7f);
    float4 g0 = reinterpret_cast<const float4*>(g)[lane];
    float4 g1 = reinterpret_cast<const float4*>(g)[64 + lane];
    float4 b0 = reinterpret_cast<const float4*>(be)[lane];
    float4 b1 = reinterpret_cast<const float4*>(be)[64 + lane];
    float* op = out + (size_t)row * 512;
    reinterpret_cast<float4*>(op)[lane] =
        make_float4(d[0] * rstd * g0.x + b0.x, d[1] * rstd * g0.y + b0.y,
                    d[2] * rstd * g0.z + b0.z, d[3] * rstd * g0.w + b0.w);
    reinterpret_cast<float4*>(op)[64 + lane] =
        make_float4(d[4] * rstd * g1.x + b1.x, d[5] * rstd * g1.y + b1.y,
                    d[6] * rstd * g1.z + b1.z, d[7] * rstd * g1.w + b1.w);
}

extern "C" void kernel_launch(void* const* d_in, const int* in_sizes, int n_in,
                              void* d_out, int out_size, void* d_ws, size_t ws_size,
                              hipStream_t stream)
{
    const float* query = (const float*)d_in[0];
    const int*   VL    = (const int*)d_in[1];
    const float* Wq = (const float*)d_in[2];  const float* bq = (const float*)d_in[3];
    const float* Wk = (const float*)d_in[4];  const float* bk = (const float*)d_in[5];
    const float* Wv = (const float*)d_in[6];  const float* bv = (const float*)d_in[7];
    const float* Wh = (const float*)d_in[8];  const float* bh = (const float*)d_in[9];
    const float* pos_k = (const float*)d_in[10];
    const float* c1w = (const float*)d_in[11]; const float* c1b = (const float*)d_in[12];
    const float* n1g = (const float*)d_in[13]; const float* n1b = (const float*)d_in[14];
    const float* c2w = (const float*)d_in[15]; const float* c2b = (const float*)d_in[16];
    const float* lng = (const float*)d_in[17]; const float* lnb = (const float*)d_in[18];

    float* ws = (float*)d_ws;
    const size_t M1 = (size_t)1 << 20;
    // f32-unit layout (peak ~31M f32 = 124 MB):
    //  [0,8M)    S1/S2/attn bf16 (16M u16), softmax in-place
    //  [8M,24M)  Y1 bf16 ch-last (32M u16)
    //  [24M,25M) Xb bf16 -> later X2 bf16
    //  [25M,26M) Qb ; [26M,27M) Kb ; [27M,28M) Vt (live thru av)
    //  [28M,30M) QPb bf16 -> later Pout f32
    //  [30M,31M) WT x4 (1M u16 = 512K f32) + pos_kb/Wf1/Wf2
    //  [31M,..)  ST/ST2
    u16* S1  = (u16*)ws;
    u16* Y1  = (u16*)(ws + 8 * M1);
    u16* Xb  = (u16*)(ws + 24 * M1);
    u16* Qb  = (u16*)(ws + 25 * M1);
    u16* Kb  = (u16*)(ws + 26 * M1);
    u16* Vt  = (u16*)(ws + 27 * M1);
    u16* QPb = (u16*)(ws + 28 * M1);
    u16* WqT = (u16*)(ws + 30 * M1);
    u16* WkT = WqT + 262144;
    u16* WvT = WkT + 262144;
    u16* WhT = WvT + 262144;
    u16* pos_kb = (u16*)(ws + 30 * M1 + 524288);
    u16* Wf1 = pos_kb + 8192;
    u16* Wf2 = Wf1 + 3584;
    float* ST  = ws + 31 * M1;
    float* ST2 = ST + 256;
    u16* X2 = Xb;
    float* Pout = ws + 28 * M1;

    hipMemsetAsync(ST, 0, 256 * sizeof(float), stream);

    k_prepx<<<1024, 256, 0, stream>>>(query, Xb);
    k_prept<<<dim3(8, 8, 4), 256, 0, stream>>>(Wq, Wk, Wv, Wh, WqT, WkT, WvT, WhT);
    k_wprep<<<1, 256, 0, stream>>>(c1w, c2w, pos_k, Wf1, Wf2, pos_kb);
    k_qkvm<<<dim3(32, 4, 3), 256, 0, stream>>>(Xb, WqT, WkT, WvT, bq, bk, bv, Qb, Kb, Vt);
    k_qposm<<<dim3(4, 64), 256, 0, stream>>>(Qb, pos_kb, QPb);
    k_scoresm<<<dim3(4, 4, 64), 256, 0, stream>>>(Qb, Kb, QPb, S1);
    k_conv1m<<<dim3(16, 16, 8), 256, 0, stream>>>(S1, Wf1, c1b, Y1, VL, ST);
    k_statfin<<<1, 128, 0, stream>>>(ST, VL, n1g, n1b, ST2);
    k_conv2m<<<dim3(16, 16, 8), 256, 0, stream>>>(Y1, ST2, Wf2, c2b, S1);
    k_softmax<<<8192, 256, 0, stream>>>(S1, VL);
    k_avm<<<dim3(4, 64), 256, 0, stream>>>(S1, Vt, X2);
    k_outm<<<dim3(32, 4), 256, 0, stream>>>(X2, WhT, bh, query, Pout);
    k_ln<<<1024, 256, 0, stream>>>(Pout, lng, lnb, (float*)d_out);
}